// Round 22
// baseline (190.535 us; speedup 1.0000x reference)
//
#include <hip/hip_runtime.h>

typedef __bf16 bf16;
typedef _Float16 f16;
typedef __bf16 bf16x8 __attribute__((ext_vector_type(8)));
typedef _Float16 f16x8 __attribute__((ext_vector_type(8)));
typedef _Float16 f16x4 __attribute__((ext_vector_type(4)));
typedef float f32x4 __attribute__((ext_vector_type(4)));
typedef unsigned int u32x4 __attribute__((ext_vector_type(4)));

#define NROWS 4096
#define DIN 1024
#define DA 512
#define NCHUNK 64   // rowsum partial column-chunks per z (QK: 16 blkN x 4 wn)

template <typename T> struct V8;
template <> struct V8<f16> { using type = f16x8; };
template <> struct V8<bf16> { using type = bf16x8; };

__device__ __forceinline__ f32x4 mfma16(f16x8 a, f16x8 b, f32x4 c) {
  return __builtin_amdgcn_mfma_f32_16x16x32_f16(a, b, c, 0, 0, 0);
}
__device__ __forceinline__ f32x4 mfma16(bf16x8 a, bf16x8 b, f32x4 c) {
  return __builtin_amdgcn_mfma_f32_16x16x32_bf16(a, b, c, 0, 0, 0);
}

__device__ __forceinline__ void gload_lds16(const void* g, void* l) {
  __builtin_amdgcn_global_load_lds((const __attribute__((address_space(1))) void*)g,
                                   (__attribute__((address_space(3))) void*)l, 16, 0, 0);
}

template <int N> __device__ __forceinline__ void vmcnt_wait() {
  if constexpr (N == 0) asm volatile("s_waitcnt vmcnt(0)" ::: "memory");
  else if constexpr (N == 1) asm volatile("s_waitcnt vmcnt(1)" ::: "memory");
  else if constexpr (N == 2) asm volatile("s_waitcnt vmcnt(2)" ::: "memory");
  else if constexpr (N == 3) asm volatile("s_waitcnt vmcnt(3)" ::: "memory");
  else if constexpr (N == 4) asm volatile("s_waitcnt vmcnt(4)" ::: "memory");
  else if constexpr (N == 6) asm volatile("s_waitcnt vmcnt(6)" ::: "memory");
  else if constexpr (N == 8) asm volatile("s_waitcnt vmcnt(8)" ::: "memory");
  else static_assert(N == 0, "unsupported vmcnt");
}

// ---------------- prep kernels ----------------

__global__ void cast_kernel(const float* __restrict__ s1, const float* __restrict__ s2,
                            f16* __restrict__ d1, f16* __restrict__ d2, int n) {
  const float* s = blockIdx.z ? s2 : s1;
  f16* d = blockIdx.z ? d2 : d1;
  int i = (blockIdx.x * blockDim.x + threadIdx.x) * 4;
  if (i < n) {
    float4 v = *(const float4*)(s + i);
    f16x4 o;
    o[0] = (f16)v.x; o[1] = (f16)v.y; o[2] = (f16)v.z; o[3] = (f16)v.w;
    *(f16x4*)(d + i) = o;
  }
}

// dst[c][r] = (f16) src[r][c]
__global__ void transpose_f32(const float* __restrict__ w0, const float* __restrict__ w1,
                              const float* __restrict__ w2, f16* __restrict__ dst,
                              size_t dstride, int rows, int cols) {
  const float* s = blockIdx.z == 0 ? w0 : (blockIdx.z == 1 ? w1 : w2);
  f16* d = dst + (size_t)blockIdx.z * dstride;
  __shared__ float tile[32][33];
  int bc = blockIdx.x * 32, br = blockIdx.y * 32;
  int tx = threadIdx.x, ty = threadIdx.y;
  for (int i = ty; i < 32; i += 8)
    tile[i][tx] = s[(size_t)(br + i) * cols + bc + tx];
  __syncthreads();
  for (int i = ty; i < 32; i += 8)
    d[(size_t)(bc + i) * rows + br + tx] = (f16)tile[tx][i];
}

// sum the NCHUNK per-column-chunk rowsum partials -> prsT[z][row]
__global__ void rowsum_reduce(const float* __restrict__ prsP, float* __restrict__ prsT) {
  int i = blockIdx.x * 256 + threadIdx.x;  // 0..8191 = z*4096 + row
  int z = i >> 12, row = i & 4095;
  const float* p = prsP + (size_t)z * NCHUNK * NROWS + row;
  float s = 0.f;
#pragma unroll
  for (int j = 0; j < NCHUNK; ++j) s += p[(size_t)j * NROWS];
  prsT[i] = s;
}

// ---------------- fused out GEMM ----------------
// out[z] = (sum_{s=0..3} pO[s*2+z]) @ woT^T + bo (f32), 128x128, BK=64, 8 waves.

__global__ __launch_bounds__(512) void out_fused(const f16* __restrict__ pO,
                                                 const f16* __restrict__ woT,
                                                 const float* __restrict__ bo,
                                                 float* __restrict__ out) {
  __shared__ __align__(16) f16 As[128 * 64];
  __shared__ __align__(16) f16 Bs[128 * 64];
  const int z = blockIdx.z;
  const size_t QS = (size_t)NROWS * DA;
  const f16* __restrict__ A0 = pO + (size_t)z * QS;
  float* __restrict__ Cg = out + (size_t)z * NROWS * DIN;

  int blkM, blkN;
  {
    const int gx = gridDim.x;
    const int nwg = gx * gridDim.y;
    const int lin = blockIdx.y * gx + blockIdx.x;
    const int q = nwg >> 3;
    const int nl = (lin & 7) * q + (lin >> 3);
    blkN = nl % gx;
    blkM = nl / gx;
  }

  const int tid = threadIdx.x;
  const int w = tid >> 6, lane = tid & 63;
  const int wr = w >> 2, wc = w & 3;
  const int lrow = lane & 15, lhi = lane >> 4;

  const size_t abase = (size_t)blkM * 128 * DA;
  const f16* Bbase = woT + (size_t)blkN * 128 * DA;

  f32x4 acc[4][2] = {};

  for (int kt = 0; kt < DA; kt += 64) {
#pragma unroll
    for (int it = 0; it < 2; ++it) {
      int cidx = (it * 8 + w) * 64 + lane;
      int row = cidx >> 3;
      int col = (cidx & 7) << 3;
      size_t off = abase + (size_t)row * DA + kt + col;
      f16x8 a = *(const f16x8*)(A0 + off);
      f16x8 b = *(const f16x8*)(A0 + 2 * QS + off);
      f16x8 c = *(const f16x8*)(A0 + 4 * QS + off);
      f16x8 d = *(const f16x8*)(A0 + 6 * QS + off);
      f16x8 s;
#pragma unroll
      for (int j = 0; j < 8; ++j)
        s[j] = (f16)(((float)a[j] + (float)b[j]) + ((float)c[j] + (float)d[j]));
      *(f16x8*)((char*)As + (size_t)cidx * 16) = s;
    }
#pragma unroll
    for (int it = 0; it < 2; ++it) {
      int cidx = (it * 8 + w) * 64 + lane;
      int row = cidx >> 3;
      int col = (cidx & 7) << 3;
      gload_lds16(Bbase + (size_t)row * DA + kt + col, (char*)Bs + (size_t)cidx * 16);
    }
    __syncthreads();

    f16x8 af[4][2], bfr[2][2];
#pragma unroll
    for (int m = 0; m < 4; ++m)
#pragma unroll
      for (int kk = 0; kk < 2; ++kk)
        af[m][kk] = *(const f16x8*)&As[(wr * 64 + m * 16 + lrow) * 64 + kk * 32 + lhi * 8];
#pragma unroll
    for (int n = 0; n < 2; ++n)
#pragma unroll
      for (int kk = 0; kk < 2; ++kk)
        bfr[n][kk] = *(const f16x8*)&Bs[(wc * 32 + n * 16 + lrow) * 64 + kk * 32 + lhi * 8];

#pragma unroll
    for (int m = 0; m < 4; ++m)
#pragma unroll
      for (int n = 0; n < 2; ++n)
#pragma unroll
        for (int kk = 0; kk < 2; ++kk)
          acc[m][n] = mfma16(af[m][kk], bfr[n][kk], acc[m][n]);
    __syncthreads();
  }

  const int row0 = blkM * 128 + wr * 64;
  const int col0 = blkN * 128 + wc * 32;
#pragma unroll
  for (int m = 0; m < 4; ++m)
#pragma unroll
    for (int n = 0; n < 2; ++n)
#pragma unroll
      for (int r = 0; r < 4; ++r) {
        int row = row0 + m * 16 + lhi * 4 + r;
        int col = col0 + n * 16 + lrow;
        Cg[(size_t)row * DIN + col] = acc[m][n][r] + bo[col];
      }
}

// ---------------- phased 256-row GEMM template ----------------
// C[256 x BN] = A[M,K] @ Bt[N,K]^T over K window [k0, k0+NT*BK).
// A addressing: element (row, k) at A[row*lda + k*aK].
// 8 waves (2M x 4N), M-interleaved wave frags. Double-buffered LDS,
// 1-tile-ahead staging with counted vmcnt; XOR swizzle + inverse-swizzled source.
// PH=4 (NFR=4 only): [B0,B1,A0,A1] one per phase. PH=2: [B..,A0 | A1].
// EPI 0: +bias; storebf=0 -> f16 row-major; storebf=1 (BN=256) -> bf16
//        TRANSPOSED store via LDS (for Vt)
// EPI 1: exp(), store bf16 into kc-TILED P layout + rowsum partials to rsO[z]
// EPI 2: split-K partial, divided by total rowsum rsO[z][row], store f16

template <typename TIN>
struct G8Args {
  const TIN* A[8];
  const TIN* B[8];
  const float* bias[8];
  void* C[8];
  float* rsO[8];
  int k0[8];
  int storebf[8];
  int lda, ldb, ldc, aK;
};

template <typename TIN, int EPI, int BN, int NT, int BK = 64, int MINW = 1, int PH = 4>
__global__ __launch_bounds__(512, MINW) void g8(G8Args<TIN> args) {
  using vec8 = typename V8<TIN>::type;
  constexpr int NFR = BN / 64;
  constexpr int FPP = 8 / PH;
  constexpr int KK = BK / 32;
  constexpr int RB = BK * 2;
  constexpr int CPR = RB / 16;
  constexpr int SWM = CPR - 1;
  constexpr int SFT = (CPR == 4) ? 1 : 0;
  constexpr int ABUF = 256 * RB;
  constexpr int BBUF = BN * RB;
  constexpr int BUFSZ = ABUF + BBUF;
  constexpr int IPU = ABUF / 2 / 8192;
  __shared__ __align__(16) char smem[2 * BUFSZ];

  static_assert(PH == 4 || PH == 2, "PH in {2,4}");

  const int z = blockIdx.z;
  const TIN* __restrict__ A = args.A[z];
  const TIN* __restrict__ B = args.B[z];
  const int lda = args.lda, ldb = args.ldb, aK = args.aK;
  const int k0 = args.k0[z];

  int blkM, blkN;
  {
    const int gx = gridDim.x;
    const int nwg = gx * gridDim.y;
    const int lin = blockIdx.y * gx + blockIdx.x;
    const int q = nwg >> 3;
    const int nl = (lin & 7) * q + (lin >> 3);
    blkN = nl % gx;
    blkM = nl / gx;
  }

  const int tid = threadIdx.x;
  const int w = tid >> 6, lane = tid & 63;
  const int wm = w & 1, wn = w >> 1;
  const int lr = lane & 15, lh = lane >> 4;

  const TIN* Abase = A + (size_t)blkM * 256 * lda;
  const TIN* Bbase = B + (size_t)blkN * BN * ldb;

  f32x4 acc[8][NFR] = {};
  vec8 af[FPP][KK], bfr[NFR][KK];

#define SWZ(r_) (((r_) >> SFT) & SWM)
#define STAGE_A(buf, hf, kt)                                                    \
  {                                                                             \
    char* dst_ = smem + (buf)*BUFSZ + (hf)*(ABUF / 2);                          \
    const TIN* src_ = Abase + (size_t)((hf)*128) * lda + (size_t)(kt)*aK;       \
    _Pragma("unroll")                                                           \
    for (int i_ = 0; i_ < IPU; ++i_) {                                          \
      int c_ = i_ * 512 + tid;                                                  \
      int r_ = c_ / CPR, q_ = c_ % CPR;                                         \
      gload_lds16(src_ + (size_t)r_ * lda + ((q_ ^ SWZ(r_)) << 3),              \
                  dst_ + c_ * 16);                                              \
    }                                                                           \
  }
#define STAGE_B(buf, hf, kt)                                                    \
  {                                                                             \
    char* dst_ = smem + (buf)*BUFSZ + ABUF + (hf)*(ABUF / 2);                   \
    const TIN* src_ = Bbase + (size_t)((hf)*128) * ldb + (kt);                  \
    _Pragma("unroll")                                                           \
    for (int i_ = 0; i_ < IPU; ++i_) {                                          \
      int c_ = i_ * 512 + tid;                                                  \
      int r_ = c_ / CPR, q_ = c_ % CPR;                                         \
      gload_lds16(src_ + (size_t)r_ * ldb + ((q_ ^ SWZ(r_)) << 3),              \
                  dst_ + c_ * 16);                                              \
    }                                                                           \
  }
#define LDA_PHASE(buf, p)                                                       \
  {                                                                             \
    char* Ab_ = smem + (buf)*BUFSZ;                                             \
    _Pragma("unroll")                                                           \
    for (int fi_ = 0; fi_ < FPP; ++fi_) {                                       \
      int row_ = (((p)*FPP + fi_) * 2 + wm) * 16 + lr;                          \
      _Pragma("unroll")                                                         \
      for (int kk_ = 0; kk_ < KK; ++kk_) {                                      \
        int cc_ = (kk_ * 4 + lh) ^ SWZ(row_);                                   \
        af[fi_][kk_] = *(const vec8*)(Ab_ + row_ * RB + cc_ * 16);              \
      }                                                                         \
    }                                                                           \
  }
#define LDB_ALL(buf)                                                            \
  {                                                                             \
    char* Bb_ = smem + (buf)*BUFSZ + ABUF;                                      \
    _Pragma("unroll")                                                           \
    for (int n_ = 0; n_ < NFR; ++n_) {                                          \
      int row_ = wn * (BN / 4) + n_ * 16 + lr;                                  \
      _Pragma("unroll")                                                         \
      for (int kk_ = 0; kk_ < KK; ++kk_) {                                      \
        int cc_ = (kk_ * 4 + lh) ^ SWZ(row_);                                   \
        bfr[n_][kk_] = *(const vec8*)(Bb_ + row_ * RB + cc_ * 16);              \
      }                                                                         \
    }                                                                           \
  }
#define MFMA_PHASE(p)                                                           \
  {                                                                             \
    _Pragma("unroll")                                                           \
    for (int fi_ = 0; fi_ < FPP; ++fi_) {                                       \
      _Pragma("unroll")                                                         \
      for (int n_ = 0; n_ < NFR; ++n_) {                                        \
        _Pragma("unroll")                                                       \
        for (int kk_ = 0; kk_ < KK; ++kk_)                                      \
          acc[(p)*FPP + fi_][n_] = mfma16(af[fi_][kk_], bfr[n_][kk_],           \
                                          acc[(p)*FPP + fi_][n_]);              \
      }                                                                         \
    }                                                                           \
  }
#define BAR() __builtin_amdgcn_s_barrier()
#define LGK0()                                          \
  asm volatile("s_waitcnt lgkmcnt(0)" ::: "memory");    \
  __builtin_amdgcn_sched_barrier(0)

  if constexpr (NFR == 4) {
    STAGE_B(0, 0, k0); STAGE_B(0, 1, k0); STAGE_A(0, 0, k0); STAGE_A(0, 1, k0);
  } else {
    STAGE_B(0, 0, k0); STAGE_A(0, 0, k0); STAGE_A(0, 1, k0);
  }
  vmcnt_wait<IPU>();
  BAR();

  for (int t = 0; t < NT; ++t) {
    const int cur = t & 1, nxt = cur ^ 1;
    const int ktn = k0 + (t + 1) * BK;
    const bool st = (t < NT - 1);
    if constexpr (PH == 4) {
      if (st) { STAGE_B(nxt, 0, ktn); }
      LDB_ALL(cur);
      LDA_PHASE(cur, 0);
      BAR(); LGK0();
      __builtin_amdgcn_s_setprio(1); MFMA_PHASE(0); __builtin_amdgcn_s_setprio(0);
      BAR();
      if (st) { STAGE_B(nxt, 1, ktn); }
      LDA_PHASE(cur, 1);
      BAR(); LGK0();
      __builtin_amdgcn_s_setprio(1); MFMA_PHASE(1); __builtin_amdgcn_s_setprio(0);
      if (st) { vmcnt_wait<2 * IPU>(); }
      else    { vmcnt_wait<0>(); }
      BAR();
      if (st) { STAGE_A(nxt, 0, ktn); }
      LDA_PHASE(cur, 2);
      BAR(); LGK0();
      __builtin_amdgcn_s_setprio(1); MFMA_PHASE(2); __builtin_amdgcn_s_setprio(0);
      BAR();
      if (st) { STAGE_A(nxt, 1, ktn); }
      LDA_PHASE(cur, 3);
      BAR(); LGK0();
      __builtin_amdgcn_s_setprio(1); MFMA_PHASE(3); __builtin_amdgcn_s_setprio(0);
      if (st) { vmcnt_wait<IPU>(); }
      BAR();
    } else {
      if (st) {
        STAGE_B(nxt, 0, ktn);
        if constexpr (NFR == 4) { STAGE_B(nxt, 1, ktn); }
        STAGE_A(nxt, 0, ktn);
      }
      LDB_ALL(cur);
      LDA_PHASE(cur, 0);
      BAR(); LGK0();
      __builtin_amdgcn_s_setprio(1); MFMA_PHASE(0); __builtin_amdgcn_s_setprio(0);
      if (st) { vmcnt_wait<(NFR == 4 ? 3 : 2) * IPU>(); }
      else    { vmcnt_wait<0>(); }
      BAR();
      if (st) { STAGE_A(nxt, 1, ktn); }
      LDA_PHASE(cur, 1);
      BAR(); LGK0();
      __builtin_amdgcn_s_setprio(1); MFMA_PHASE(1); __builtin_amdgcn_s_setprio(0);
      if (st) { vmcnt_wait<IPU>(); }
      BAR();
    }
  }

  // ---- epilogue ----
  const int row0 = blkM * 256;
  const int col0 = blkN * BN + wn * (BN / 4);
  const int ldc = args.ldc;
  if constexpr (EPI == 1) {
    // exp + store into kc-tiled P [kc][4096][64] + rowsum partials.
    bf16* Pt = (bf16*)args.C[z] + (size_t)(blkN * 4 + wn) * ((size_t)NROWS * 64);
#pragma unroll
    for (int a = 0; a < 8; ++a) {
      float rsv[4] = {0.f, 0.f, 0.f, 0.f};
#pragma unroll
      for (int n = 0; n < NFR; ++n) {
#pragma unroll
        for (int rr = 0; rr < 4; ++rr) {
          int row = row0 + (a * 2 + wm) * 16 + lh * 4 + rr;
          float e = __expf(acc[a][n][rr]);
          Pt[(size_t)row * 64 + n * 16 + lr] = (bf16)e;
          rsv[rr] += e;
        }
      }
#pragma unroll
      for (int rr = 0; rr < 4; ++rr) {
        float s = rsv[rr];
        s += __shfl_xor(s, 1);
        s += __shfl_xor(s, 2);
        s += __shfl_xor(s, 4);
        s += __shfl_xor(s, 8);
        if (lr == 0) {
          int row = row0 + (a * 2 + wm) * 16 + lh * 4 + rr;
          args.rsO[z][((size_t)blkN * 4 + wn) * NROWS + row] = s;
        }
      }
    }
  } else if constexpr (EPI == 2) {
    // split-K partial divided by TOTAL rowsum (rsO[z] = prsT slice), f16 store
#pragma unroll
    for (int a = 0; a < 8; ++a) {
#pragma unroll
      for (int rr = 0; rr < 4; ++rr) {
        int row = row0 + (a * 2 + wm) * 16 + lh * 4 + rr;
        float rinv = 1.0f / args.rsO[z][row];
#pragma unroll
        for (int n = 0; n < NFR; ++n) {
          int col = col0 + n * 16 + lr;
          ((f16*)args.C[z])[(size_t)row * ldc + col] = (f16)(acc[a][n][rr] * rinv);
        }
      }
    }
  } else if constexpr (EPI == 0 && BN == 256) {
    if (args.storebf[z]) {
      // bias + TRANSPOSED bf16 store via LDS (dest = vt[col][row], ld=NROWS).
#pragma unroll
      for (int a = 0; a < 8; ++a) {
#pragma unroll
        for (int n = 0; n < NFR; ++n) {
#pragma unroll
          for (int rr = 0; rr < 4; ++rr) {
            int row_l = (a * 2 + wm) * 16 + lh * 4 + rr;
            int col_l = wn * 64 + n * 16 + lr;
            float b = acc[a][n][rr] + args.bias[z][blkN * 256 + col_l];
            int byte = col_l * 512 + (((row_l >> 3) ^ (col_l & 31)) << 4) + (row_l & 7) * 2;
            *(bf16*)(smem + byte) = (bf16)b;
          }
        }
      }
      __syncthreads();
      bf16* vt = (bf16*)args.C[z];
#pragma unroll
      for (int i = 0; i < 16; ++i) {
        int cidx = i * 512 + tid;
        int c = cidx >> 5, ch = cidx & 31;
        u32x4 v = *(const u32x4*)(smem + c * 512 + ((ch ^ (c & 31)) << 4));
        size_t dst = (size_t)(blkN * 256 + c) * NROWS + blkM * 256 + ch * 8;
        *(u32x4*)(vt + dst) = v;
      }
    } else {
#pragma unroll
      for (int a = 0; a < 8; ++a) {
#pragma unroll
        for (int n = 0; n < NFR; ++n) {
#pragma unroll
          for (int rr = 0; rr < 4; ++rr) {
            int row = row0 + (a * 2 + wm) * 16 + lh * 4 + rr;
            int col = col0 + n * 16 + lr;
            ((f16*)args.C[z])[(size_t)row * ldc + col] =
                (f16)(acc[a][n][rr] + args.bias[z][col]);
          }
        }
      }
    }
  } else {
#pragma unroll
    for (int a = 0; a < 8; ++a) {
#pragma unroll
      for (int n = 0; n < NFR; ++n) {
#pragma unroll
        for (int rr = 0; rr < 4; ++rr) {
          int row = row0 + (a * 2 + wm) * 16 + lh * 4 + rr;
          int col = col0 + n * 16 + lr;
          float v = acc[a][n][rr];
          if constexpr (EPI == 0) {
            ((f16*)args.C[z])[(size_t)row * ldc + col] = (f16)(v + args.bias[z][col]);
          } else {
            ((float*)args.C[z])[(size_t)row * ldc + col] = v + args.bias[z][col];
          }
        }
      }
    }
  }
#undef SWZ
#undef STAGE_A
#undef STAGE_B
#undef LDA_PHASE
#undef LDB_ALL
#undef MFMA_PHASE
#undef BAR
#undef LGK0
}

// ---------------- launch ----------------

extern "C" void kernel_launch(void* const* d_in, const int* in_sizes, int n_in,
                              void* d_out, int out_size, void* d_ws, size_t ws_size,
                              hipStream_t stream) {
  const float* in1 = (const float*)d_in[0];
  const float* in2 = (const float*)d_in[1];
  const float* Wq = (const float*)d_in[2];
  const float* bq = (const float*)d_in[3];
  const float* Wk = (const float*)d_in[4];
  const float* bk = (const float*)d_in[5];
  const float* Wv = (const float*)d_in[6];
  const float* bv = (const float*)d_in[7];
  const float* Wo = (const float*)d_in[8];
  const float* bo = (const float*)d_in[9];
  float* out = (float*)d_out;

  const size_t IN_E = (size_t)NROWS * DIN;   // 4M
  const size_t WT_E = (size_t)DA * DIN;      // 512K
  const size_t QS = (size_t)NROWS * DA;      // 2M
  const size_t PS = (size_t)NROWS * NROWS;   // 16M

  f16* qk = (f16*)d_ws;                      // 16 MB (dead after QK)
  f16* in_hf = qk + 4 * QS;                  // 16 MB (dead after proj)
  bf16* vv = (bf16*)(in_hf + 2 * IN_E);      // 8 MB (rowsum scratch)
  f16* wt = (f16*)(vv + 2 * QS);             // 3 MB
  f16* woT = wt + 3 * WT_E;                  // 1 MB
  bf16* vt = (bf16*)(woT + WT_E);            // 8 MB (written directly by proj)
  bf16* P = vt + 2 * QS;                     // 64 MB, kc-tiled [kc][4096][64]
  f16* pO = (f16*)d_ws;                      // 32 MB f16 (8 slices), aliases qk+in_hf
  float* prsP = (float*)vv;                  // 2 MB rowsum partials
  float* prsT = prsP + 2 * (size_t)NCHUNK * NROWS;  // 32 KB totals

  // 1. cast inputs to fp16
  cast_kernel<<<dim3((unsigned)(IN_E / 1024), 1, 2), dim3(256), 0, stream>>>(
      in1, in2, in_hf, in_hf + IN_E, (int)IN_E);

  // 2. transpose-cast weights
  transpose_f32<<<dim3(DA / 32, DIN / 32, 3), dim3(32, 8), 0, stream>>>(
      Wq, Wk, Wv, wt, WT_E, DIN, DA);
  transpose_f32<<<dim3(DIN / 32, DA / 32, 1), dim3(32, 8), 0, stream>>>(
      Wo, Wo, Wo, woT, 0, DA, DIN);

  // 3. projections (2-phase 256x256): z = Q1,K1,Q2,K2,V1,V2
  //    V (z=4,5) stored DIRECTLY TRANSPOSED into vt (bf16) via LDS epilogue.
  {
    G8Args<f16> a{};
    const float* bs[3] = {bq, bk, bv};
    for (int zi = 0; zi < 6; ++zi) {
      int which = (zi < 4) ? (zi & 1) : 2;
      int src = (zi < 4) ? (zi >> 1) : (zi - 4);
      a.A[zi] = in_hf + (size_t)src * IN_E;
      a.B[zi] = wt + (size_t)which * WT_E;
      a.bias[zi] = bs[which];
      a.C[zi] = (zi < 4) ? (void*)(qk + (size_t)zi * QS) : (void*)(vt + (size_t)(zi - 4) * QS);
      a.storebf[zi] = (zi >= 4);
      a.k0[zi] = 0;
    }
    a.lda = DIN; a.ldb = DIN; a.ldc = DA; a.aK = 1;
    g8<f16, 0, 256, 16, 64, 1, 2><<<dim3(2, 16, 6), dim3(512), 0, stream>>>(a);
  }

  // 4. P = exp(Q @ K^T) into kc-tiled layout + rowsum partials (2-phase 256x256)
  {
    G8Args<f16> a{};
    a.A[0] = qk + 0 * QS; a.B[0] = qk + 3 * QS; a.C[0] = P;
    a.A[1] = qk + 2 * QS; a.B[1] = qk + 1 * QS; a.C[1] = P + PS;
    a.rsO[0] = prsP;
    a.rsO[1] = prsP + (size_t)NCHUNK * NROWS;
    a.k0[0] = a.k0[1] = 0;
    a.lda = DA; a.ldb = DA; a.ldc = NROWS; a.aK = 1;
    g8<f16, 1, 256, 8, 64, 1, 2><<<dim3(16, 16, 2), dim3(512), 0, stream>>>(a);
  }

  // 4b. reduce rowsum partials -> prsT
  rowsum_reduce<<<dim3(32), dim3(256), 0, stream>>>(prsP, prsT);

  // 5. PV split-K=4 partials, / prsT, f16 (2-phase 256x256, 32 MFMA/phase):
  //    z = s*2 + pair, grid (2,16,8) = 256 blocks = 1/CU, all CUs busy.
  {
    G8Args<bf16> a{};
    for (int i = 0; i < 8; ++i) {
      int pair = i & 1, s = i >> 1;
      a.A[i] = P + (size_t)pair * PS;
      a.B[i] = vt + (size_t)(pair ^ 1) * QS;
      a.C[i] = pO + (size_t)i * QS;
      a.rsO[i] = prsT + (size_t)pair * NROWS;
      a.k0[i] = s * 1024;
      a.storebf[i] = 0;
    }
    a.lda = 64; a.ldb = NROWS; a.ldc = DA; a.aK = NROWS;
    g8<bf16, 2, 256, 16, 64, 1, 2><<<dim3(2, 16, 8), dim3(512), 0, stream>>>(a);
  }

  // 6. out = (sum of 4 pO slices) @ Wo + bo (fused merge + GEMM, f32)
  out_fused<<<dim3(DIN / 128, NROWS / 128, 2), dim3(512), 0, stream>>>(
      pO, woT, bo, out);
}

// Round 23
// 185.164 us; speedup vs baseline: 1.0290x; 1.0290x over previous
//
#include <hip/hip_runtime.h>

typedef __bf16 bf16;
typedef _Float16 f16;
typedef __bf16 bf16x8 __attribute__((ext_vector_type(8)));
typedef _Float16 f16x8 __attribute__((ext_vector_type(8)));
typedef _Float16 f16x4 __attribute__((ext_vector_type(4)));
typedef float f32x4 __attribute__((ext_vector_type(4)));
typedef unsigned int u32x4 __attribute__((ext_vector_type(4)));

#define NROWS 4096
#define DIN 1024
#define DA 512
#define NCHUNK 64   // rowsum partial column-chunks per z (QK: 16 blkN x 4 wn)

template <typename T> struct V8;
template <> struct V8<f16> { using type = f16x8; };
template <> struct V8<bf16> { using type = bf16x8; };

__device__ __forceinline__ f32x4 mfma16(f16x8 a, f16x8 b, f32x4 c) {
  return __builtin_amdgcn_mfma_f32_16x16x32_f16(a, b, c, 0, 0, 0);
}
__device__ __forceinline__ f32x4 mfma16(bf16x8 a, bf16x8 b, f32x4 c) {
  return __builtin_amdgcn_mfma_f32_16x16x32_bf16(a, b, c, 0, 0, 0);
}

__device__ __forceinline__ void gload_lds16(const void* g, void* l) {
  __builtin_amdgcn_global_load_lds((const __attribute__((address_space(1))) void*)g,
                                   (__attribute__((address_space(3))) void*)l, 16, 0, 0);
}

template <int N> __device__ __forceinline__ void vmcnt_wait() {
  if constexpr (N == 0) asm volatile("s_waitcnt vmcnt(0)" ::: "memory");
  else if constexpr (N == 1) asm volatile("s_waitcnt vmcnt(1)" ::: "memory");
  else if constexpr (N == 2) asm volatile("s_waitcnt vmcnt(2)" ::: "memory");
  else if constexpr (N == 3) asm volatile("s_waitcnt vmcnt(3)" ::: "memory");
  else if constexpr (N == 4) asm volatile("s_waitcnt vmcnt(4)" ::: "memory");
  else if constexpr (N == 6) asm volatile("s_waitcnt vmcnt(6)" ::: "memory");
  else if constexpr (N == 8) asm volatile("s_waitcnt vmcnt(8)" ::: "memory");
  else static_assert(N == 0, "unsupported vmcnt");
}

// ---------------- unified prep kernel ----------------
// flat grid of 10240 x 256 threads:
//   [0, 8192):        cast in1/in2 f32 -> f16 (z = bid>>12)
//   [8192, 9728):     transpose-cast Wq/Wk/Wv [1024,512] -> wt [512][1024]
//   [9728, 10240):    transpose-cast Wo [512,1024] -> woT [1024][512]

__global__ __launch_bounds__(256) void prep_kernel(
    const float* __restrict__ in1, const float* __restrict__ in2,
    const float* __restrict__ Wq, const float* __restrict__ Wk,
    const float* __restrict__ Wv, const float* __restrict__ Wo,
    f16* __restrict__ in_hf, f16* __restrict__ wt, f16* __restrict__ woT) {
  __shared__ float tile[32][33];
  const int bid = blockIdx.x;
  const int tid = threadIdx.x;
  if (bid < 8192) {
    int z = bid >> 12, b = bid & 4095;
    const float* s = z ? in2 : in1;
    f16* d = in_hf + (size_t)z * ((size_t)NROWS * DIN);
    int i = (b * 256 + tid) * 4;
    float4 v = *(const float4*)(s + i);
    f16x4 o;
    o[0] = (f16)v.x; o[1] = (f16)v.y; o[2] = (f16)v.z; o[3] = (f16)v.w;
    *(f16x4*)(d + i) = o;
  } else {
    int b = bid - 8192;
    int tx = tid & 31, ty = tid >> 5;
    const float* s;
    f16* d;
    int rows, cols, bc, br;
    if (b < 1536) {
      int z = b / 512, rem = b % 512;
      int by = rem / 16, bx = rem % 16;
      s = (z == 0) ? Wq : ((z == 1) ? Wk : Wv);
      d = wt + (size_t)z * ((size_t)DA * DIN);
      rows = DIN; cols = DA; bc = bx * 32; br = by * 32;
    } else {
      int rem = b - 1536;
      int by = rem / 32, bx = rem % 32;
      s = Wo; d = woT;
      rows = DA; cols = DIN; bc = bx * 32; br = by * 32;
    }
    for (int i = ty; i < 32; i += 8)
      tile[i][tx] = s[(size_t)(br + i) * cols + bc + tx];
    __syncthreads();
    for (int i = ty; i < 32; i += 8)
      d[(size_t)(bc + i) * rows + br + tx] = (f16)tile[tx][i];
  }
}

// sum the NCHUNK per-column-chunk rowsum partials -> prsT[z][row]
__global__ void rowsum_reduce(const float* __restrict__ prsP, float* __restrict__ prsT) {
  int i = blockIdx.x * 256 + threadIdx.x;  // 0..8191 = z*4096 + row
  int z = i >> 12, row = i & 4095;
  const float* p = prsP + (size_t)z * NCHUNK * NROWS + row;
  float s = 0.f;
#pragma unroll
  for (int j = 0; j < NCHUNK; ++j) s += p[(size_t)j * NROWS];
  prsT[i] = s;
}

// ---------------- fused out GEMM ----------------
// out[z] = (pO[z] + pO[2+z]) @ woT^T + bo (f32), 128x128, BK=64, 8 waves.

__global__ __launch_bounds__(512) void out_fused(const f16* __restrict__ pO,
                                                 const f16* __restrict__ woT,
                                                 const float* __restrict__ bo,
                                                 float* __restrict__ out) {
  __shared__ __align__(16) f16 As[128 * 64];
  __shared__ __align__(16) f16 Bs[128 * 64];
  const int z = blockIdx.z;
  const size_t QS = (size_t)NROWS * DA;
  const f16* __restrict__ A0 = pO + (size_t)z * QS;
  const f16* __restrict__ A1 = pO + (size_t)(2 + z) * QS;
  float* __restrict__ Cg = out + (size_t)z * NROWS * DIN;

  int blkM, blkN;
  {
    const int gx = gridDim.x;
    const int nwg = gx * gridDim.y;
    const int lin = blockIdx.y * gx + blockIdx.x;
    const int q = nwg >> 3;
    const int nl = (lin & 7) * q + (lin >> 3);
    blkN = nl % gx;
    blkM = nl / gx;
  }

  const int tid = threadIdx.x;
  const int w = tid >> 6, lane = tid & 63;
  const int wr = w >> 2, wc = w & 3;
  const int lrow = lane & 15, lhi = lane >> 4;

  const size_t abase = (size_t)blkM * 128 * DA;
  const f16* Bbase = woT + (size_t)blkN * 128 * DA;

  f32x4 acc[4][2] = {};

  for (int kt = 0; kt < DA; kt += 64) {
#pragma unroll
    for (int it = 0; it < 2; ++it) {
      int cidx = (it * 8 + w) * 64 + lane;
      int row = cidx >> 3;
      int col = (cidx & 7) << 3;
      size_t off = abase + (size_t)row * DA + kt + col;
      f16x8 a = *(const f16x8*)(A0 + off);
      f16x8 b = *(const f16x8*)(A1 + off);
      f16x8 s;
#pragma unroll
      for (int j = 0; j < 8; ++j) s[j] = (f16)((float)a[j] + (float)b[j]);
      *(f16x8*)((char*)As + (size_t)cidx * 16) = s;
    }
#pragma unroll
    for (int it = 0; it < 2; ++it) {
      int cidx = (it * 8 + w) * 64 + lane;
      int row = cidx >> 3;
      int col = (cidx & 7) << 3;
      gload_lds16(Bbase + (size_t)row * DA + kt + col, (char*)Bs + (size_t)cidx * 16);
    }
    __syncthreads();

    f16x8 af[4][2], bfr[2][2];
#pragma unroll
    for (int m = 0; m < 4; ++m)
#pragma unroll
      for (int kk = 0; kk < 2; ++kk)
        af[m][kk] = *(const f16x8*)&As[(wr * 64 + m * 16 + lrow) * 64 + kk * 32 + lhi * 8];
#pragma unroll
    for (int n = 0; n < 2; ++n)
#pragma unroll
      for (int kk = 0; kk < 2; ++kk)
        bfr[n][kk] = *(const f16x8*)&Bs[(wc * 32 + n * 16 + lrow) * 64 + kk * 32 + lhi * 8];

#pragma unroll
    for (int m = 0; m < 4; ++m)
#pragma unroll
      for (int n = 0; n < 2; ++n)
#pragma unroll
        for (int kk = 0; kk < 2; ++kk)
          acc[m][n] = mfma16(af[m][kk], bfr[n][kk], acc[m][n]);
    __syncthreads();
  }

  const int row0 = blkM * 128 + wr * 64;
  const int col0 = blkN * 128 + wc * 32;
#pragma unroll
  for (int m = 0; m < 4; ++m)
#pragma unroll
    for (int n = 0; n < 2; ++n)
#pragma unroll
      for (int r = 0; r < 4; ++r) {
        int row = row0 + m * 16 + lhi * 4 + r;
        int col = col0 + n * 16 + lrow;
        Cg[(size_t)row * DIN + col] = acc[m][n][r] + bo[col];
      }
}

// ---------------- phased 256-row GEMM template ----------------
// C[256 x BN] = A[M,K] @ Bt[N,K]^T over K window [k0, k0+NT*BK).
// A addressing: element (row, k) at A[row*lda + k*aK].
// 8 waves (2M x 4N), M-interleaved wave frags. Double-buffered LDS,
// 1-tile-ahead staging with counted vmcnt; XOR swizzle + inverse-swizzled source.
// PH=4 (NFR=4 only): [B0,B1,A0,A1] one per phase. PH=2: [B..,A0 | A1].
// EPI 0: +bias; storebf=0 -> f16 row-major; storebf=1 (BN=256) -> bf16
//        TRANSPOSED store via LDS (for Vt)
// EPI 1: exp(), store bf16 into kc-TILED P layout + rowsum partials to rsO[z]
// EPI 2: split-K partial, divided by total rowsum rsO[z][row], store f16

template <typename TIN>
struct G8Args {
  const TIN* A[6];
  const TIN* B[6];
  const float* bias[6];
  void* C[6];
  float* rsO[6];
  int k0[6];
  int storebf[6];
  int lda, ldb, ldc, aK;
};

template <typename TIN, int EPI, int BN, int NT, int BK = 64, int MINW = 1, int PH = 4>
__global__ __launch_bounds__(512, MINW) void g8(G8Args<TIN> args) {
  using vec8 = typename V8<TIN>::type;
  constexpr int NFR = BN / 64;
  constexpr int FPP = 8 / PH;
  constexpr int KK = BK / 32;
  constexpr int RB = BK * 2;
  constexpr int CPR = RB / 16;
  constexpr int SWM = CPR - 1;
  constexpr int SFT = (CPR == 4) ? 1 : 0;
  constexpr int ABUF = 256 * RB;
  constexpr int BBUF = BN * RB;
  constexpr int BUFSZ = ABUF + BBUF;
  constexpr int IPU = ABUF / 2 / 8192;
  __shared__ __align__(16) char smem[2 * BUFSZ];

  static_assert(PH == 4 || PH == 2, "PH in {2,4}");

  const int z = blockIdx.z;
  const TIN* __restrict__ A = args.A[z];
  const TIN* __restrict__ B = args.B[z];
  const int lda = args.lda, ldb = args.ldb, aK = args.aK;
  const int k0 = args.k0[z];

  int blkM, blkN;
  {
    const int gx = gridDim.x;
    const int nwg = gx * gridDim.y;
    const int lin = blockIdx.y * gx + blockIdx.x;
    const int q = nwg >> 3;
    const int nl = (lin & 7) * q + (lin >> 3);
    blkN = nl % gx;
    blkM = nl / gx;
  }

  const int tid = threadIdx.x;
  const int w = tid >> 6, lane = tid & 63;
  const int wm = w & 1, wn = w >> 1;
  const int lr = lane & 15, lh = lane >> 4;

  const TIN* Abase = A + (size_t)blkM * 256 * lda;
  const TIN* Bbase = B + (size_t)blkN * BN * ldb;

  f32x4 acc[8][NFR] = {};
  vec8 af[FPP][KK], bfr[NFR][KK];

#define SWZ(r_) (((r_) >> SFT) & SWM)
#define STAGE_A(buf, hf, kt)                                                    \
  {                                                                             \
    char* dst_ = smem + (buf)*BUFSZ + (hf)*(ABUF / 2);                          \
    const TIN* src_ = Abase + (size_t)((hf)*128) * lda + (size_t)(kt)*aK;       \
    _Pragma("unroll")                                                           \
    for (int i_ = 0; i_ < IPU; ++i_) {                                          \
      int c_ = i_ * 512 + tid;                                                  \
      int r_ = c_ / CPR, q_ = c_ % CPR;                                         \
      gload_lds16(src_ + (size_t)r_ * lda + ((q_ ^ SWZ(r_)) << 3),              \
                  dst_ + c_ * 16);                                              \
    }                                                                           \
  }
#define STAGE_B(buf, hf, kt)                                                    \
  {                                                                             \
    char* dst_ = smem + (buf)*BUFSZ + ABUF + (hf)*(ABUF / 2);                   \
    const TIN* src_ = Bbase + (size_t)((hf)*128) * ldb + (kt);                  \
    _Pragma("unroll")                                                           \
    for (int i_ = 0; i_ < IPU; ++i_) {                                          \
      int c_ = i_ * 512 + tid;                                                  \
      int r_ = c_ / CPR, q_ = c_ % CPR;                                         \
      gload_lds16(src_ + (size_t)r_ * ldb + ((q_ ^ SWZ(r_)) << 3),              \
                  dst_ + c_ * 16);                                              \
    }                                                                           \
  }
#define LDA_PHASE(buf, p)                                                       \
  {                                                                             \
    char* Ab_ = smem + (buf)*BUFSZ;                                             \
    _Pragma("unroll")                                                           \
    for (int fi_ = 0; fi_ < FPP; ++fi_) {                                       \
      int row_ = (((p)*FPP + fi_) * 2 + wm) * 16 + lr;                          \
      _Pragma("unroll")                                                         \
      for (int kk_ = 0; kk_ < KK; ++kk_) {                                      \
        int cc_ = (kk_ * 4 + lh) ^ SWZ(row_);                                   \
        af[fi_][kk_] = *(const vec8*)(Ab_ + row_ * RB + cc_ * 16);              \
      }                                                                         \
    }                                                                           \
  }
#define LDB_ALL(buf)                                                            \
  {                                                                             \
    char* Bb_ = smem + (buf)*BUFSZ + ABUF;                                      \
    _Pragma("unroll")                                                           \
    for (int n_ = 0; n_ < NFR; ++n_) {                                          \
      int row_ = wn * (BN / 4) + n_ * 16 + lr;                                  \
      _Pragma("unroll")                                                         \
      for (int kk_ = 0; kk_ < KK; ++kk_) {                                      \
        int cc_ = (kk_ * 4 + lh) ^ SWZ(row_);                                   \
        bfr[n_][kk_] = *(const vec8*)(Bb_ + row_ * RB + cc_ * 16);              \
      }                                                                         \
    }                                                                           \
  }
#define MFMA_PHASE(p)                                                           \
  {                                                                             \
    _Pragma("unroll")                                                           \
    for (int fi_ = 0; fi_ < FPP; ++fi_) {                                       \
      _Pragma("unroll")                                                         \
      for (int n_ = 0; n_ < NFR; ++n_) {                                        \
        _Pragma("unroll")                                                       \
        for (int kk_ = 0; kk_ < KK; ++kk_)                                      \
          acc[(p)*FPP + fi_][n_] = mfma16(af[fi_][kk_], bfr[n_][kk_],           \
                                          acc[(p)*FPP + fi_][n_]);              \
      }                                                                         \
    }                                                                           \
  }
#define BAR() __builtin_amdgcn_s_barrier()
#define LGK0()                                          \
  asm volatile("s_waitcnt lgkmcnt(0)" ::: "memory");    \
  __builtin_amdgcn_sched_barrier(0)

  if constexpr (NFR == 4) {
    STAGE_B(0, 0, k0); STAGE_B(0, 1, k0); STAGE_A(0, 0, k0); STAGE_A(0, 1, k0);
  } else {
    STAGE_B(0, 0, k0); STAGE_A(0, 0, k0); STAGE_A(0, 1, k0);
  }
  vmcnt_wait<IPU>();
  BAR();

  for (int t = 0; t < NT; ++t) {
    const int cur = t & 1, nxt = cur ^ 1;
    const int ktn = k0 + (t + 1) * BK;
    const bool st = (t < NT - 1);
    if constexpr (PH == 4) {
      if (st) { STAGE_B(nxt, 0, ktn); }
      LDB_ALL(cur);
      LDA_PHASE(cur, 0);
      BAR(); LGK0();
      __builtin_amdgcn_s_setprio(1); MFMA_PHASE(0); __builtin_amdgcn_s_setprio(0);
      BAR();
      if (st) { STAGE_B(nxt, 1, ktn); }
      LDA_PHASE(cur, 1);
      BAR(); LGK0();
      __builtin_amdgcn_s_setprio(1); MFMA_PHASE(1); __builtin_amdgcn_s_setprio(0);
      if (st) { vmcnt_wait<2 * IPU>(); }
      else    { vmcnt_wait<0>(); }
      BAR();
      if (st) { STAGE_A(nxt, 0, ktn); }
      LDA_PHASE(cur, 2);
      BAR(); LGK0();
      __builtin_amdgcn_s_setprio(1); MFMA_PHASE(2); __builtin_amdgcn_s_setprio(0);
      BAR();
      if (st) { STAGE_A(nxt, 1, ktn); }
      LDA_PHASE(cur, 3);
      BAR(); LGK0();
      __builtin_amdgcn_s_setprio(1); MFMA_PHASE(3); __builtin_amdgcn_s_setprio(0);
      if (st) { vmcnt_wait<IPU>(); }
      BAR();
    } else {
      if (st) {
        STAGE_B(nxt, 0, ktn);
        if constexpr (NFR == 4) { STAGE_B(nxt, 1, ktn); }
        STAGE_A(nxt, 0, ktn);
      }
      LDB_ALL(cur);
      LDA_PHASE(cur, 0);
      BAR(); LGK0();
      __builtin_amdgcn_s_setprio(1); MFMA_PHASE(0); __builtin_amdgcn_s_setprio(0);
      if (st) { vmcnt_wait<(NFR == 4 ? 3 : 2) * IPU>(); }
      else    { vmcnt_wait<0>(); }
      BAR();
      if (st) { STAGE_A(nxt, 1, ktn); }
      LDA_PHASE(cur, 1);
      BAR(); LGK0();
      __builtin_amdgcn_s_setprio(1); MFMA_PHASE(1); __builtin_amdgcn_s_setprio(0);
      if (st) { vmcnt_wait<IPU>(); }
      BAR();
    }
  }

  // ---- epilogue ----
  const int row0 = blkM * 256;
  const int col0 = blkN * BN + wn * (BN / 4);
  const int ldc = args.ldc;
  if constexpr (EPI == 1) {
    // exp + store into kc-tiled P [kc][4096][64] + rowsum partials.
    bf16* Pt = (bf16*)args.C[z] + (size_t)(blkN * 4 + wn) * ((size_t)NROWS * 64);
#pragma unroll
    for (int a = 0; a < 8; ++a) {
      float rsv[4] = {0.f, 0.f, 0.f, 0.f};
#pragma unroll
      for (int n = 0; n < NFR; ++n) {
#pragma unroll
        for (int rr = 0; rr < 4; ++rr) {
          int row = row0 + (a * 2 + wm) * 16 + lh * 4 + rr;
          float e = __expf(acc[a][n][rr]);
          Pt[(size_t)row * 64 + n * 16 + lr] = (bf16)e;
          rsv[rr] += e;
        }
      }
#pragma unroll
      for (int rr = 0; rr < 4; ++rr) {
        float s = rsv[rr];
        s += __shfl_xor(s, 1);
        s += __shfl_xor(s, 2);
        s += __shfl_xor(s, 4);
        s += __shfl_xor(s, 8);
        if (lr == 0) {
          int row = row0 + (a * 2 + wm) * 16 + lh * 4 + rr;
          args.rsO[z][((size_t)blkN * 4 + wn) * NROWS + row] = s;
        }
      }
    }
  } else if constexpr (EPI == 2) {
    // split-K partial divided by TOTAL rowsum (rsO[z] = prsT slice), f16 store
#pragma unroll
    for (int a = 0; a < 8; ++a) {
#pragma unroll
      for (int rr = 0; rr < 4; ++rr) {
        int row = row0 + (a * 2 + wm) * 16 + lh * 4 + rr;
        float rinv = 1.0f / args.rsO[z][row];
#pragma unroll
        for (int n = 0; n < NFR; ++n) {
          int col = col0 + n * 16 + lr;
          ((f16*)args.C[z])[(size_t)row * ldc + col] = (f16)(acc[a][n][rr] * rinv);
        }
      }
    }
  } else if constexpr (EPI == 0 && BN == 256) {
    if (args.storebf[z]) {
      // bias + TRANSPOSED bf16 store via LDS (dest = vt[col][row], ld=NROWS).
#pragma unroll
      for (int a = 0; a < 8; ++a) {
#pragma unroll
        for (int n = 0; n < NFR; ++n) {
#pragma unroll
          for (int rr = 0; rr < 4; ++rr) {
            int row_l = (a * 2 + wm) * 16 + lh * 4 + rr;
            int col_l = wn * 64 + n * 16 + lr;
            float b = acc[a][n][rr] + args.bias[z][blkN * 256 + col_l];
            int byte = col_l * 512 + (((row_l >> 3) ^ (col_l & 31)) << 4) + (row_l & 7) * 2;
            *(bf16*)(smem + byte) = (bf16)b;
          }
        }
      }
      __syncthreads();
      bf16* vt = (bf16*)args.C[z];
#pragma unroll
      for (int i = 0; i < 16; ++i) {
        int cidx = i * 512 + tid;
        int c = cidx >> 5, ch = cidx & 31;
        u32x4 v = *(const u32x4*)(smem + c * 512 + ((ch ^ (c & 31)) << 4));
        size_t dst = (size_t)(blkN * 256 + c) * NROWS + blkM * 256 + ch * 8;
        *(u32x4*)(vt + dst) = v;
      }
    } else {
#pragma unroll
      for (int a = 0; a < 8; ++a) {
#pragma unroll
        for (int n = 0; n < NFR; ++n) {
#pragma unroll
          for (int rr = 0; rr < 4; ++rr) {
            int row = row0 + (a * 2 + wm) * 16 + lh * 4 + rr;
            int col = col0 + n * 16 + lr;
            ((f16*)args.C[z])[(size_t)row * ldc + col] =
                (f16)(acc[a][n][rr] + args.bias[z][col]);
          }
        }
      }
    }
  } else {
#pragma unroll
    for (int a = 0; a < 8; ++a) {
#pragma unroll
      for (int n = 0; n < NFR; ++n) {
#pragma unroll
        for (int rr = 0; rr < 4; ++rr) {
          int row = row0 + (a * 2 + wm) * 16 + lh * 4 + rr;
          int col = col0 + n * 16 + lr;
          float v = acc[a][n][rr];
          if constexpr (EPI == 0) {
            ((f16*)args.C[z])[(size_t)row * ldc + col] = (f16)(v + args.bias[z][col]);
          } else {
            ((float*)args.C[z])[(size_t)row * ldc + col] = v + args.bias[z][col];
          }
        }
      }
    }
  }
#undef SWZ
#undef STAGE_A
#undef STAGE_B
#undef LDA_PHASE
#undef LDB_ALL
#undef MFMA_PHASE
#undef BAR
#undef LGK0
}

// ---------------- launch ----------------

extern "C" void kernel_launch(void* const* d_in, const int* in_sizes, int n_in,
                              void* d_out, int out_size, void* d_ws, size_t ws_size,
                              hipStream_t stream) {
  const float* in1 = (const float*)d_in[0];
  const float* in2 = (const float*)d_in[1];
  const float* Wq = (const float*)d_in[2];
  const float* bq = (const float*)d_in[3];
  const float* Wk = (const float*)d_in[4];
  const float* bk = (const float*)d_in[5];
  const float* Wv = (const float*)d_in[6];
  const float* bv = (const float*)d_in[7];
  const float* Wo = (const float*)d_in[8];
  const float* bo = (const float*)d_in[9];
  float* out = (float*)d_out;

  const size_t IN_E = (size_t)NROWS * DIN;   // 4M
  const size_t WT_E = (size_t)DA * DIN;      // 512K
  const size_t QS = (size_t)NROWS * DA;      // 2M
  const size_t PS = (size_t)NROWS * NROWS;   // 16M

  f16* qk = (f16*)d_ws;                      // 16 MB (dead after QK)
  f16* in_hf = qk + 4 * QS;                  // 16 MB (dead after proj)
  bf16* vv = (bf16*)(in_hf + 2 * IN_E);      // 8 MB (rowsum scratch)
  f16* wt = (f16*)(vv + 2 * QS);             // 3 MB
  f16* woT = wt + 3 * WT_E;                  // 1 MB
  bf16* vt = (bf16*)(woT + WT_E);            // 8 MB (written directly by proj)
  bf16* P = vt + 2 * QS;                     // 64 MB, kc-tiled [kc][4096][64]
  f16* pO = (f16*)d_ws;                      // 16 MB f16 (4 slices), aliases qk
  float* prsP = (float*)vv;                  // 2 MB rowsum partials
  float* prsT = prsP + 2 * (size_t)NCHUNK * NROWS;  // 32 KB totals

  // 1. unified prep: cast inputs + transpose-cast weights (single launch)
  prep_kernel<<<dim3(10240), dim3(256), 0, stream>>>(
      in1, in2, Wq, Wk, Wv, Wo, in_hf, wt, woT);

  // 2. projections (2-phase 256x256): z = Q1,K1,Q2,K2,V1,V2
  //    V (z=4,5) stored DIRECTLY TRANSPOSED into vt (bf16) via LDS epilogue.
  {
    G8Args<f16> a{};
    const float* bs[3] = {bq, bk, bv};
    for (int zi = 0; zi < 6; ++zi) {
      int which = (zi < 4) ? (zi & 1) : 2;
      int src = (zi < 4) ? (zi >> 1) : (zi - 4);
      a.A[zi] = in_hf + (size_t)src * IN_E;
      a.B[zi] = wt + (size_t)which * WT_E;
      a.bias[zi] = bs[which];
      a.C[zi] = (zi < 4) ? (void*)(qk + (size_t)zi * QS) : (void*)(vt + (size_t)(zi - 4) * QS);
      a.storebf[zi] = (zi >= 4);
      a.k0[zi] = 0;
    }
    a.lda = DIN; a.ldb = DIN; a.ldc = DA; a.aK = 1;
    g8<f16, 0, 256, 16, 64, 1, 2><<<dim3(2, 16, 6), dim3(512), 0, stream>>>(a);
  }

  // 3. P = exp(Q @ K^T) into kc-tiled layout + rowsum partials (2-phase 256x256)
  {
    G8Args<f16> a{};
    a.A[0] = qk + 0 * QS; a.B[0] = qk + 3 * QS; a.C[0] = P;
    a.A[1] = qk + 2 * QS; a.B[1] = qk + 1 * QS; a.C[1] = P + PS;
    a.rsO[0] = prsP;
    a.rsO[1] = prsP + (size_t)NCHUNK * NROWS;
    a.k0[0] = a.k0[1] = 0;
    a.lda = DA; a.ldb = DA; a.ldc = NROWS; a.aK = 1;
    g8<f16, 1, 256, 8, 64, 1, 2><<<dim3(16, 16, 2), dim3(512), 0, stream>>>(a);
  }

  // 3b. reduce rowsum partials -> prsT
  rowsum_reduce<<<dim3(32), dim3(256), 0, stream>>>(prsP, prsT);

  // 4. PV split-K partials, / prsT, f16 (2-phase 256x128); A = kc-tiled P
  {
    G8Args<bf16> a{};
    for (int i = 0; i < 4; ++i) {
      int pair = i & 1, s = i >> 1;
      a.A[i] = P + (size_t)pair * PS;
      a.B[i] = vt + (size_t)(pair ^ 1) * QS;
      a.C[i] = pO + (size_t)i * QS;
      a.rsO[i] = prsT + (size_t)pair * NROWS;
      a.k0[i] = s * 2048;
      a.storebf[i] = 0;
    }
    a.lda = 64; a.ldb = NROWS; a.ldc = DA; a.aK = NROWS;
    g8<bf16, 2, 128, 32, 64, 1, 2><<<dim3(4, 16, 4), dim3(512), 0, stream>>>(a);
  }

  // 5. out = (pO[z]+pO[2+z]) @ Wo + bo (fused merge + GEMM, f32)
  out_fused<<<dim3(DIN / 128, NROWS / 128, 2), dim3(512), 0, stream>>>(
      pO, woT, bo, out);
}

// Round 24
// 167.525 us; speedup vs baseline: 1.1374x; 1.1053x over previous
//
#include <hip/hip_runtime.h>

typedef __bf16 bf16;
typedef _Float16 f16;
typedef __bf16 bf16x8 __attribute__((ext_vector_type(8)));
typedef _Float16 f16x8 __attribute__((ext_vector_type(8)));
typedef _Float16 f16x4 __attribute__((ext_vector_type(4)));
typedef float f32x4 __attribute__((ext_vector_type(4)));
typedef unsigned int u32x4 __attribute__((ext_vector_type(4)));

#define NROWS 4096
#define DIN 1024
#define DA 512
#define NCHUNK 64   // rowsum partial column-chunks per z (QK: 16 blkN x 4 wn)

template <typename T> struct V8;
template <> struct V8<f16> { using type = f16x8; };
template <> struct V8<bf16> { using type = bf16x8; };

__device__ __forceinline__ f32x4 mfma16(f16x8 a, f16x8 b, f32x4 c) {
  return __builtin_amdgcn_mfma_f32_16x16x32_f16(a, b, c, 0, 0, 0);
}
__device__ __forceinline__ f32x4 mfma16(bf16x8 a, bf16x8 b, f32x4 c) {
  return __builtin_amdgcn_mfma_f32_16x16x32_bf16(a, b, c, 0, 0, 0);
}

__device__ __forceinline__ void gload_lds16(const void* g, void* l) {
  __builtin_amdgcn_global_load_lds((const __attribute__((address_space(1))) void*)g,
                                   (__attribute__((address_space(3))) void*)l, 16, 0, 0);
}

template <int N> __device__ __forceinline__ void vmcnt_wait() {
  if constexpr (N == 0) asm volatile("s_waitcnt vmcnt(0)" ::: "memory");
  else if constexpr (N == 1) asm volatile("s_waitcnt vmcnt(1)" ::: "memory");
  else if constexpr (N == 2) asm volatile("s_waitcnt vmcnt(2)" ::: "memory");
  else if constexpr (N == 3) asm volatile("s_waitcnt vmcnt(3)" ::: "memory");
  else if constexpr (N == 4) asm volatile("s_waitcnt vmcnt(4)" ::: "memory");
  else if constexpr (N == 6) asm volatile("s_waitcnt vmcnt(6)" ::: "memory");
  else if constexpr (N == 8) asm volatile("s_waitcnt vmcnt(8)" ::: "memory");
  else static_assert(N == 0, "unsupported vmcnt");
}

// ---------------- unified prep kernel ----------------
// flat grid of 10240 x 256 threads:
//   [0, 8192):        cast in1/in2 f32 -> f16 (z = bid>>12)
//   [8192, 9728):     transpose-cast Wq/Wk/Wv [1024,512] -> wt [512][1024]
//   [9728, 10240):    transpose-cast Wo [512,1024] -> woT [1024][512]

__global__ __launch_bounds__(256) void prep_kernel(
    const float* __restrict__ in1, const float* __restrict__ in2,
    const float* __restrict__ Wq, const float* __restrict__ Wk,
    const float* __restrict__ Wv, const float* __restrict__ Wo,
    f16* __restrict__ in_hf, f16* __restrict__ wt, f16* __restrict__ woT) {
  __shared__ float tile[32][33];
  const int bid = blockIdx.x;
  const int tid = threadIdx.x;
  if (bid < 8192) {
    int z = bid >> 12, b = bid & 4095;
    const float* s = z ? in2 : in1;
    f16* d = in_hf + (size_t)z * ((size_t)NROWS * DIN);
    int i = (b * 256 + tid) * 4;
    float4 v = *(const float4*)(s + i);
    f16x4 o;
    o[0] = (f16)v.x; o[1] = (f16)v.y; o[2] = (f16)v.z; o[3] = (f16)v.w;
    *(f16x4*)(d + i) = o;
  } else {
    int b = bid - 8192;
    int tx = tid & 31, ty = tid >> 5;
    const float* s;
    f16* d;
    int rows, cols, bc, br;
    if (b < 1536) {
      int z = b / 512, rem = b % 512;
      int by = rem / 16, bx = rem % 16;
      s = (z == 0) ? Wq : ((z == 1) ? Wk : Wv);
      d = wt + (size_t)z * ((size_t)DA * DIN);
      rows = DIN; cols = DA; bc = bx * 32; br = by * 32;
    } else {
      int rem = b - 1536;
      int by = rem / 32, bx = rem % 32;
      s = Wo; d = woT;
      rows = DA; cols = DIN; bc = bx * 32; br = by * 32;
    }
    for (int i = ty; i < 32; i += 8)
      tile[i][tx] = s[(size_t)(br + i) * cols + bc + tx];
    __syncthreads();
    for (int i = ty; i < 32; i += 8)
      d[(size_t)(bc + i) * rows + br + tx] = (f16)tile[tx][i];
  }
}

// ---------------- fused out GEMM ----------------
// out[z] = (pO[z] + pO[2+z]) @ woT^T + bo (f32), 128x128, BK=64, 8 waves.

__global__ __launch_bounds__(512) void out_fused(const f16* __restrict__ pO,
                                                 const f16* __restrict__ woT,
                                                 const float* __restrict__ bo,
                                                 float* __restrict__ out) {
  __shared__ __align__(16) f16 As[128 * 64];
  __shared__ __align__(16) f16 Bs[128 * 64];
  const int z = blockIdx.z;
  const size_t QS = (size_t)NROWS * DA;
  const f16* __restrict__ A0 = pO + (size_t)z * QS;
  const f16* __restrict__ A1 = pO + (size_t)(2 + z) * QS;
  float* __restrict__ Cg = out + (size_t)z * NROWS * DIN;

  int blkM, blkN;
  {
    const int gx = gridDim.x;
    const int nwg = gx * gridDim.y;
    const int lin = blockIdx.y * gx + blockIdx.x;
    const int q = nwg >> 3;
    const int nl = (lin & 7) * q + (lin >> 3);
    blkN = nl % gx;
    blkM = nl / gx;
  }

  const int tid = threadIdx.x;
  const int w = tid >> 6, lane = tid & 63;
  const int wr = w >> 2, wc = w & 3;
  const int lrow = lane & 15, lhi = lane >> 4;

  const size_t abase = (size_t)blkM * 128 * DA;
  const f16* Bbase = woT + (size_t)blkN * 128 * DA;

  f32x4 acc[4][2] = {};

  for (int kt = 0; kt < DA; kt += 64) {
#pragma unroll
    for (int it = 0; it < 2; ++it) {
      int cidx = (it * 8 + w) * 64 + lane;
      int row = cidx >> 3;
      int col = (cidx & 7) << 3;
      size_t off = abase + (size_t)row * DA + kt + col;
      f16x8 a = *(const f16x8*)(A0 + off);
      f16x8 b = *(const f16x8*)(A1 + off);
      f16x8 s;
#pragma unroll
      for (int j = 0; j < 8; ++j) s[j] = (f16)((float)a[j] + (float)b[j]);
      *(f16x8*)((char*)As + (size_t)cidx * 16) = s;
    }
#pragma unroll
    for (int it = 0; it < 2; ++it) {
      int cidx = (it * 8 + w) * 64 + lane;
      int row = cidx >> 3;
      int col = (cidx & 7) << 3;
      gload_lds16(Bbase + (size_t)row * DA + kt + col, (char*)Bs + (size_t)cidx * 16);
    }
    __syncthreads();

    f16x8 af[4][2], bfr[2][2];
#pragma unroll
    for (int m = 0; m < 4; ++m)
#pragma unroll
      for (int kk = 0; kk < 2; ++kk)
        af[m][kk] = *(const f16x8*)&As[(wr * 64 + m * 16 + lrow) * 64 + kk * 32 + lhi * 8];
#pragma unroll
    for (int n = 0; n < 2; ++n)
#pragma unroll
      for (int kk = 0; kk < 2; ++kk)
        bfr[n][kk] = *(const f16x8*)&Bs[(wc * 32 + n * 16 + lrow) * 64 + kk * 32 + lhi * 8];

#pragma unroll
    for (int m = 0; m < 4; ++m)
#pragma unroll
      for (int n = 0; n < 2; ++n)
#pragma unroll
        for (int kk = 0; kk < 2; ++kk)
          acc[m][n] = mfma16(af[m][kk], bfr[n][kk], acc[m][n]);
    __syncthreads();
  }

  const int row0 = blkM * 128 + wr * 64;
  const int col0 = blkN * 128 + wc * 32;
#pragma unroll
  for (int m = 0; m < 4; ++m)
#pragma unroll
    for (int n = 0; n < 2; ++n)
#pragma unroll
      for (int r = 0; r < 4; ++r) {
        int row = row0 + m * 16 + lhi * 4 + r;
        int col = col0 + n * 16 + lrow;
        Cg[(size_t)row * DIN + col] = acc[m][n][r] + bo[col];
      }
}

// ---------------- phased 256-row GEMM template ----------------
// C[256 x BN] = A[M,K] @ Bt[N,K]^T over K window [k0, k0+NT*BK).
// A addressing: element (row, k) at A[row*lda + k*aK].
// 8 waves (2M x 4N), M-interleaved wave frags. Double-buffered LDS,
// 1-tile-ahead staging with counted vmcnt; XOR swizzle + inverse-swizzled source.
// PH=4 (NFR=4 only): [B0,B1,A0,A1] one per phase. PH=2: [B..,A0 | A1].
// EPI 0: +bias; storebf=0 -> f16 row-major; storebf=1 (BN=256) -> bf16
//        TRANSPOSED store via LDS (for Vt)
// EPI 1: exp(), store bf16 into kc-TILED P layout + rowsum partials to rsO[z]
// EPI 2: split-K partial / rowsum (BLOCK-LOCAL reduce of rsO[z] partials
//        over NCHUNK chunks, cached in dead LDS), store f16

template <typename TIN>
struct G8Args {
  const TIN* A[6];
  const TIN* B[6];
  const float* bias[6];
  void* C[6];
  float* rsO[6];
  int k0[6];
  int storebf[6];
  int lda, ldb, ldc, aK;
};

template <typename TIN, int EPI, int BN, int NT, int BK = 64, int MINW = 1, int PH = 4>
__global__ __launch_bounds__(512, MINW) void g8(G8Args<TIN> args) {
  using vec8 = typename V8<TIN>::type;
  constexpr int NFR = BN / 64;
  constexpr int FPP = 8 / PH;
  constexpr int KK = BK / 32;
  constexpr int RB = BK * 2;
  constexpr int CPR = RB / 16;
  constexpr int SWM = CPR - 1;
  constexpr int SFT = (CPR == 4) ? 1 : 0;
  constexpr int ABUF = 256 * RB;
  constexpr int BBUF = BN * RB;
  constexpr int BUFSZ = ABUF + BBUF;
  constexpr int IPU = ABUF / 2 / 8192;
  __shared__ __align__(16) char smem[2 * BUFSZ];

  static_assert(PH == 4 || PH == 2, "PH in {2,4}");

  const int z = blockIdx.z;
  const TIN* __restrict__ A = args.A[z];
  const TIN* __restrict__ B = args.B[z];
  const int lda = args.lda, ldb = args.ldb, aK = args.aK;
  const int k0 = args.k0[z];

  int blkM, blkN;
  {
    const int gx = gridDim.x;
    const int nwg = gx * gridDim.y;
    const int lin = blockIdx.y * gx + blockIdx.x;
    const int q = nwg >> 3;
    const int nl = (lin & 7) * q + (lin >> 3);
    blkN = nl % gx;
    blkM = nl / gx;
  }

  const int tid = threadIdx.x;
  const int w = tid >> 6, lane = tid & 63;
  const int wm = w & 1, wn = w >> 1;
  const int lr = lane & 15, lh = lane >> 4;

  const TIN* Abase = A + (size_t)blkM * 256 * lda;
  const TIN* Bbase = B + (size_t)blkN * BN * ldb;

  f32x4 acc[8][NFR] = {};
  vec8 af[FPP][KK], bfr[NFR][KK];

#define SWZ(r_) (((r_) >> SFT) & SWM)
#define STAGE_A(buf, hf, kt)                                                    \
  {                                                                             \
    char* dst_ = smem + (buf)*BUFSZ + (hf)*(ABUF / 2);                          \
    const TIN* src_ = Abase + (size_t)((hf)*128) * lda + (size_t)(kt)*aK;       \
    _Pragma("unroll")                                                           \
    for (int i_ = 0; i_ < IPU; ++i_) {                                          \
      int c_ = i_ * 512 + tid;                                                  \
      int r_ = c_ / CPR, q_ = c_ % CPR;                                         \
      gload_lds16(src_ + (size_t)r_ * lda + ((q_ ^ SWZ(r_)) << 3),              \
                  dst_ + c_ * 16);                                              \
    }                                                                           \
  }
#define STAGE_B(buf, hf, kt)                                                    \
  {                                                                             \
    char* dst_ = smem + (buf)*BUFSZ + ABUF + (hf)*(ABUF / 2);                   \
    const TIN* src_ = Bbase + (size_t)((hf)*128) * ldb + (kt);                  \
    _Pragma("unroll")                                                           \
    for (int i_ = 0; i_ < IPU; ++i_) {                                          \
      int c_ = i_ * 512 + tid;                                                  \
      int r_ = c_ / CPR, q_ = c_ % CPR;                                         \
      gload_lds16(src_ + (size_t)r_ * ldb + ((q_ ^ SWZ(r_)) << 3),              \
                  dst_ + c_ * 16);                                              \
    }                                                                           \
  }
#define LDA_PHASE(buf, p)                                                       \
  {                                                                             \
    char* Ab_ = smem + (buf)*BUFSZ;                                             \
    _Pragma("unroll")                                                           \
    for (int fi_ = 0; fi_ < FPP; ++fi_) {                                       \
      int row_ = (((p)*FPP + fi_) * 2 + wm) * 16 + lr;                          \
      _Pragma("unroll")                                                         \
      for (int kk_ = 0; kk_ < KK; ++kk_) {                                      \
        int cc_ = (kk_ * 4 + lh) ^ SWZ(row_);                                   \
        af[fi_][kk_] = *(const vec8*)(Ab_ + row_ * RB + cc_ * 16);              \
      }                                                                         \
    }                                                                           \
  }
#define LDB_ALL(buf)                                                            \
  {                                                                             \
    char* Bb_ = smem + (buf)*BUFSZ + ABUF;                                      \
    _Pragma("unroll")                                                           \
    for (int n_ = 0; n_ < NFR; ++n_) {                                          \
      int row_ = wn * (BN / 4) + n_ * 16 + lr;                                  \
      _Pragma("unroll")                                                         \
      for (int kk_ = 0; kk_ < KK; ++kk_) {                                      \
        int cc_ = (kk_ * 4 + lh) ^ SWZ(row_);                                   \
        bfr[n_][kk_] = *(const vec8*)(Bb_ + row_ * RB + cc_ * 16);              \
      }                                                                         \
    }                                                                           \
  }
#define MFMA_PHASE(p)                                                           \
  {                                                                             \
    _Pragma("unroll")                                                           \
    for (int fi_ = 0; fi_ < FPP; ++fi_) {                                       \
      _Pragma("unroll")                                                         \
      for (int n_ = 0; n_ < NFR; ++n_) {                                        \
        _Pragma("unroll")                                                       \
        for (int kk_ = 0; kk_ < KK; ++kk_)                                      \
          acc[(p)*FPP + fi_][n_] = mfma16(af[fi_][kk_], bfr[n_][kk_],           \
                                          acc[(p)*FPP + fi_][n_]);              \
      }                                                                         \
    }                                                                           \
  }
#define BAR() __builtin_amdgcn_s_barrier()
#define LGK0()                                          \
  asm volatile("s_waitcnt lgkmcnt(0)" ::: "memory");    \
  __builtin_amdgcn_sched_barrier(0)

  if constexpr (NFR == 4) {
    STAGE_B(0, 0, k0); STAGE_B(0, 1, k0); STAGE_A(0, 0, k0); STAGE_A(0, 1, k0);
  } else {
    STAGE_B(0, 0, k0); STAGE_A(0, 0, k0); STAGE_A(0, 1, k0);
  }
  vmcnt_wait<IPU>();
  BAR();

  for (int t = 0; t < NT; ++t) {
    const int cur = t & 1, nxt = cur ^ 1;
    const int ktn = k0 + (t + 1) * BK;
    const bool st = (t < NT - 1);
    if constexpr (PH == 4) {
      if (st) { STAGE_B(nxt, 0, ktn); }
      LDB_ALL(cur);
      LDA_PHASE(cur, 0);
      BAR(); LGK0();
      __builtin_amdgcn_s_setprio(1); MFMA_PHASE(0); __builtin_amdgcn_s_setprio(0);
      BAR();
      if (st) { STAGE_B(nxt, 1, ktn); }
      LDA_PHASE(cur, 1);
      BAR(); LGK0();
      __builtin_amdgcn_s_setprio(1); MFMA_PHASE(1); __builtin_amdgcn_s_setprio(0);
      if (st) { vmcnt_wait<2 * IPU>(); }
      else    { vmcnt_wait<0>(); }
      BAR();
      if (st) { STAGE_A(nxt, 0, ktn); }
      LDA_PHASE(cur, 2);
      BAR(); LGK0();
      __builtin_amdgcn_s_setprio(1); MFMA_PHASE(2); __builtin_amdgcn_s_setprio(0);
      BAR();
      if (st) { STAGE_A(nxt, 1, ktn); }
      LDA_PHASE(cur, 3);
      BAR(); LGK0();
      __builtin_amdgcn_s_setprio(1); MFMA_PHASE(3); __builtin_amdgcn_s_setprio(0);
      if (st) { vmcnt_wait<IPU>(); }
      BAR();
    } else {
      if (st) {
        STAGE_B(nxt, 0, ktn);
        if constexpr (NFR == 4) { STAGE_B(nxt, 1, ktn); }
        STAGE_A(nxt, 0, ktn);
      }
      LDB_ALL(cur);
      LDA_PHASE(cur, 0);
      BAR(); LGK0();
      __builtin_amdgcn_s_setprio(1); MFMA_PHASE(0); __builtin_amdgcn_s_setprio(0);
      if (st) { vmcnt_wait<(NFR == 4 ? 3 : 2) * IPU>(); }
      else    { vmcnt_wait<0>(); }
      BAR();
      if (st) { STAGE_A(nxt, 1, ktn); }
      LDA_PHASE(cur, 1);
      BAR(); LGK0();
      __builtin_amdgcn_s_setprio(1); MFMA_PHASE(1); __builtin_amdgcn_s_setprio(0);
      if (st) { vmcnt_wait<IPU>(); }
      BAR();
    }
  }

  // ---- epilogue ----
  const int row0 = blkM * 256;
  const int col0 = blkN * BN + wn * (BN / 4);
  const int ldc = args.ldc;
  if constexpr (EPI == 1) {
    // exp + store into kc-tiled P [kc][4096][64] + rowsum partials.
    bf16* Pt = (bf16*)args.C[z] + (size_t)(blkN * 4 + wn) * ((size_t)NROWS * 64);
#pragma unroll
    for (int a = 0; a < 8; ++a) {
      float rsv[4] = {0.f, 0.f, 0.f, 0.f};
#pragma unroll
      for (int n = 0; n < NFR; ++n) {
#pragma unroll
        for (int rr = 0; rr < 4; ++rr) {
          int row = row0 + (a * 2 + wm) * 16 + lh * 4 + rr;
          float e = __expf(acc[a][n][rr]);
          Pt[(size_t)row * 64 + n * 16 + lr] = (bf16)e;
          rsv[rr] += e;
        }
      }
#pragma unroll
      for (int rr = 0; rr < 4; ++rr) {
        float s = rsv[rr];
        s += __shfl_xor(s, 1);
        s += __shfl_xor(s, 2);
        s += __shfl_xor(s, 4);
        s += __shfl_xor(s, 8);
        if (lr == 0) {
          int row = row0 + (a * 2 + wm) * 16 + lh * 4 + rr;
          args.rsO[z][((size_t)blkN * 4 + wn) * NROWS + row] = s;
        }
      }
    }
  } else if constexpr (EPI == 2) {
    // block-local rowsum reduce into dead LDS (all smem reads done after
    // the K-loop's final barrier), then split-K partial / rowsum, f16 store.
    float* rsinv = (float*)smem;
    if (tid < 256) {
      const float* p = args.rsO[z] + (row0 + tid);
      float s0 = 0.f, s1 = 0.f, s2 = 0.f, s3 = 0.f;
#pragma unroll
      for (int j = 0; j < NCHUNK; j += 4) {
        s0 += p[(size_t)j * NROWS];
        s1 += p[(size_t)(j + 1) * NROWS];
        s2 += p[(size_t)(j + 2) * NROWS];
        s3 += p[(size_t)(j + 3) * NROWS];
      }
      rsinv[tid] = 1.0f / ((s0 + s1) + (s2 + s3));
    }
    __syncthreads();
#pragma unroll
    for (int a = 0; a < 8; ++a) {
#pragma unroll
      for (int rr = 0; rr < 4; ++rr) {
        int row_l = (a * 2 + wm) * 16 + lh * 4 + rr;
        float rinv = rsinv[row_l];
#pragma unroll
        for (int n = 0; n < NFR; ++n) {
          int col = col0 + n * 16 + lr;
          ((f16*)args.C[z])[(size_t)(row0 + row_l) * ldc + col] =
              (f16)(acc[a][n][rr] * rinv);
        }
      }
    }
  } else if constexpr (EPI == 0 && BN == 256) {
    if (args.storebf[z]) {
      // bias + TRANSPOSED bf16 store via LDS (dest = vt[col][row], ld=NROWS).
#pragma unroll
      for (int a = 0; a < 8; ++a) {
#pragma unroll
        for (int n = 0; n < NFR; ++n) {
#pragma unroll
          for (int rr = 0; rr < 4; ++rr) {
            int row_l = (a * 2 + wm) * 16 + lh * 4 + rr;
            int col_l = wn * 64 + n * 16 + lr;
            float b = acc[a][n][rr] + args.bias[z][blkN * 256 + col_l];
            int byte = col_l * 512 + (((row_l >> 3) ^ (col_l & 31)) << 4) + (row_l & 7) * 2;
            *(bf16*)(smem + byte) = (bf16)b;
          }
        }
      }
      __syncthreads();
      bf16* vt = (bf16*)args.C[z];
#pragma unroll
      for (int i = 0; i < 16; ++i) {
        int cidx = i * 512 + tid;
        int c = cidx >> 5, ch = cidx & 31;
        u32x4 v = *(const u32x4*)(smem + c * 512 + ((ch ^ (c & 31)) << 4));
        size_t dst = (size_t)(blkN * 256 + c) * NROWS + blkM * 256 + ch * 8;
        *(u32x4*)(vt + dst) = v;
      }
    } else {
#pragma unroll
      for (int a = 0; a < 8; ++a) {
#pragma unroll
        for (int n = 0; n < NFR; ++n) {
#pragma unroll
          for (int rr = 0; rr < 4; ++rr) {
            int row = row0 + (a * 2 + wm) * 16 + lh * 4 + rr;
            int col = col0 + n * 16 + lr;
            ((f16*)args.C[z])[(size_t)row * ldc + col] =
                (f16)(acc[a][n][rr] + args.bias[z][col]);
          }
        }
      }
    }
  } else {
#pragma unroll
    for (int a = 0; a < 8; ++a) {
#pragma unroll
      for (int n = 0; n < NFR; ++n) {
#pragma unroll
        for (int rr = 0; rr < 4; ++rr) {
          int row = row0 + (a * 2 + wm) * 16 + lh * 4 + rr;
          int col = col0 + n * 16 + lr;
          float v = acc[a][n][rr];
          if constexpr (EPI == 0) {
            ((f16*)args.C[z])[(size_t)row * ldc + col] = (f16)(v + args.bias[z][col]);
          } else {
            ((float*)args.C[z])[(size_t)row * ldc + col] = v + args.bias[z][col];
          }
        }
      }
    }
  }
#undef SWZ
#undef STAGE_A
#undef STAGE_B
#undef LDA_PHASE
#undef LDB_ALL
#undef MFMA_PHASE
#undef BAR
#undef LGK0
}

// ---------------- launch ----------------

extern "C" void kernel_launch(void* const* d_in, const int* in_sizes, int n_in,
                              void* d_out, int out_size, void* d_ws, size_t ws_size,
                              hipStream_t stream) {
  const float* in1 = (const float*)d_in[0];
  const float* in2 = (const float*)d_in[1];
  const float* Wq = (const float*)d_in[2];
  const float* bq = (const float*)d_in[3];
  const float* Wk = (const float*)d_in[4];
  const float* bk = (const float*)d_in[5];
  const float* Wv = (const float*)d_in[6];
  const float* bv = (const float*)d_in[7];
  const float* Wo = (const float*)d_in[8];
  const float* bo = (const float*)d_in[9];
  float* out = (float*)d_out;

  const size_t IN_E = (size_t)NROWS * DIN;   // 4M
  const size_t WT_E = (size_t)DA * DIN;      // 512K
  const size_t QS = (size_t)NROWS * DA;      // 2M
  const size_t PS = (size_t)NROWS * NROWS;   // 16M

  f16* qk = (f16*)d_ws;                      // 16 MB (dead after QK)
  f16* in_hf = qk + 4 * QS;                  // 16 MB (dead after proj)
  bf16* vv = (bf16*)(in_hf + 2 * IN_E);      // 8 MB (rowsum scratch)
  f16* wt = (f16*)(vv + 2 * QS);             // 3 MB
  f16* woT = wt + 3 * WT_E;                  // 1 MB
  bf16* vt = (bf16*)(woT + WT_E);            // 8 MB (written directly by proj)
  bf16* P = vt + 2 * QS;                     // 64 MB, kc-tiled [kc][4096][64]
  f16* pO = (f16*)d_ws;                      // 16 MB f16 (4 slices), aliases qk
  float* prsP = (float*)vv;                  // 2 MB rowsum partials

  // 1. unified prep: cast inputs + transpose-cast weights (single launch)
  prep_kernel<<<dim3(10240), dim3(256), 0, stream>>>(
      in1, in2, Wq, Wk, Wv, Wo, in_hf, wt, woT);

  // 2. projections (2-phase 256x256): z = Q1,K1,Q2,K2,V1,V2
  //    V (z=4,5) stored DIRECTLY TRANSPOSED into vt (bf16) via LDS epilogue.
  {
    G8Args<f16> a{};
    const float* bs[3] = {bq, bk, bv};
    for (int zi = 0; zi < 6; ++zi) {
      int which = (zi < 4) ? (zi & 1) : 2;
      int src = (zi < 4) ? (zi >> 1) : (zi - 4);
      a.A[zi] = in_hf + (size_t)src * IN_E;
      a.B[zi] = wt + (size_t)which * WT_E;
      a.bias[zi] = bs[which];
      a.C[zi] = (zi < 4) ? (void*)(qk + (size_t)zi * QS) : (void*)(vt + (size_t)(zi - 4) * QS);
      a.storebf[zi] = (zi >= 4);
      a.k0[zi] = 0;
    }
    a.lda = DIN; a.ldb = DIN; a.ldc = DA; a.aK = 1;
    g8<f16, 0, 256, 16, 64, 1, 2><<<dim3(2, 16, 6), dim3(512), 0, stream>>>(a);
  }

  // 3. P = exp(Q @ K^T) into kc-tiled layout + rowsum partials (2-phase 256x256)
  {
    G8Args<f16> a{};
    a.A[0] = qk + 0 * QS; a.B[0] = qk + 3 * QS; a.C[0] = P;
    a.A[1] = qk + 2 * QS; a.B[1] = qk + 1 * QS; a.C[1] = P + PS;
    a.rsO[0] = prsP;
    a.rsO[1] = prsP + (size_t)NCHUNK * NROWS;
    a.k0[0] = a.k0[1] = 0;
    a.lda = DA; a.ldb = DA; a.ldc = NROWS; a.aK = 1;
    g8<f16, 1, 256, 8, 64, 1, 2><<<dim3(16, 16, 2), dim3(512), 0, stream>>>(a);
  }

  // 4. PV split-K partials, block-local rowsum reduce, f16 (2-phase 256x128)
  {
    G8Args<bf16> a{};
    for (int i = 0; i < 4; ++i) {
      int pair = i & 1, s = i >> 1;
      a.A[i] = P + (size_t)pair * PS;
      a.B[i] = vt + (size_t)(pair ^ 1) * QS;
      a.C[i] = pO + (size_t)i * QS;
      a.rsO[i] = prsP + (size_t)pair * NCHUNK * NROWS;
      a.k0[i] = s * 2048;
      a.storebf[i] = 0;
    }
    a.lda = 64; a.ldb = NROWS; a.ldc = DA; a.aK = NROWS;
    g8<bf16, 2, 128, 32, 64, 1, 2><<<dim3(4, 16, 4), dim3(512), 0, stream>>>(a);
  }

  // 5. out = (pO[z]+pO[2+z]) @ Wo + bo (fused merge + GEMM, f32)
  out_fused<<<dim3(DIN / 128, NROWS / 128, 2), dim3(512), 0, stream>>>(
      pO, woT, bo, out);
}

// Round 25
// 167.295 us; speedup vs baseline: 1.1389x; 1.0014x over previous
//
#include <hip/hip_runtime.h>

typedef __bf16 bf16;
typedef _Float16 f16;
typedef __bf16 bf16x8 __attribute__((ext_vector_type(8)));
typedef _Float16 f16x8 __attribute__((ext_vector_type(8)));
typedef _Float16 f16x4 __attribute__((ext_vector_type(4)));
typedef float f32x4 __attribute__((ext_vector_type(4)));
typedef unsigned int u32x4 __attribute__((ext_vector_type(4)));

#define NROWS 4096
#define DIN 1024
#define DA 512
#define NCHUNK 64   // rowsum partial column-chunks per z (QK: 16 blkN x 4 wn)

template <typename T> struct V8;
template <> struct V8<f16> { using type = f16x8; };
template <> struct V8<bf16> { using type = bf16x8; };

__device__ __forceinline__ f32x4 mfma16(f16x8 a, f16x8 b, f32x4 c) {
  return __builtin_amdgcn_mfma_f32_16x16x32_f16(a, b, c, 0, 0, 0);
}
__device__ __forceinline__ f32x4 mfma16(bf16x8 a, bf16x8 b, f32x4 c) {
  return __builtin_amdgcn_mfma_f32_16x16x32_bf16(a, b, c, 0, 0, 0);
}

__device__ __forceinline__ void gload_lds16(const void* g, void* l) {
  __builtin_amdgcn_global_load_lds((const __attribute__((address_space(1))) void*)g,
                                   (__attribute__((address_space(3))) void*)l, 16, 0, 0);
}

template <int N> __device__ __forceinline__ void vmcnt_wait() {
  if constexpr (N == 0) asm volatile("s_waitcnt vmcnt(0)" ::: "memory");
  else if constexpr (N == 1) asm volatile("s_waitcnt vmcnt(1)" ::: "memory");
  else if constexpr (N == 2) asm volatile("s_waitcnt vmcnt(2)" ::: "memory");
  else if constexpr (N == 3) asm volatile("s_waitcnt vmcnt(3)" ::: "memory");
  else if constexpr (N == 4) asm volatile("s_waitcnt vmcnt(4)" ::: "memory");
  else if constexpr (N == 6) asm volatile("s_waitcnt vmcnt(6)" ::: "memory");
  else if constexpr (N == 8) asm volatile("s_waitcnt vmcnt(8)" ::: "memory");
  else static_assert(N == 0, "unsupported vmcnt");
}

// ---------------- unified prep kernel ----------------
// flat grid of 10240 x 256 threads:
//   [0, 8192):        cast in1/in2 f32 -> f16 (z = bid>>12)
//   [8192, 9728):     transpose-cast Wq/Wk/Wv [1024,512] -> wt [512][1024]
//   [9728, 10240):    transpose-cast Wo [512,1024] -> woT [1024][512]

__global__ __launch_bounds__(256) void prep_kernel(
    const float* __restrict__ in1, const float* __restrict__ in2,
    const float* __restrict__ Wq, const float* __restrict__ Wk,
    const float* __restrict__ Wv, const float* __restrict__ Wo,
    f16* __restrict__ in_hf, f16* __restrict__ wt, f16* __restrict__ woT) {
  __shared__ float tile[32][33];
  const int bid = blockIdx.x;
  const int tid = threadIdx.x;
  if (bid < 8192) {
    int z = bid >> 12, b = bid & 4095;
    const float* s = z ? in2 : in1;
    f16* d = in_hf + (size_t)z * ((size_t)NROWS * DIN);
    int i = (b * 256 + tid) * 4;
    float4 v = *(const float4*)(s + i);
    f16x4 o;
    o[0] = (f16)v.x; o[1] = (f16)v.y; o[2] = (f16)v.z; o[3] = (f16)v.w;
    *(f16x4*)(d + i) = o;
  } else {
    int b = bid - 8192;
    int tx = tid & 31, ty = tid >> 5;
    const float* s;
    f16* d;
    int rows, cols, bc, br;
    if (b < 1536) {
      int z = b / 512, rem = b % 512;
      int by = rem / 16, bx = rem % 16;
      s = (z == 0) ? Wq : ((z == 1) ? Wk : Wv);
      d = wt + (size_t)z * ((size_t)DA * DIN);
      rows = DIN; cols = DA; bc = bx * 32; br = by * 32;
    } else {
      int rem = b - 1536;
      int by = rem / 32, bx = rem % 32;
      s = Wo; d = woT;
      rows = DA; cols = DIN; bc = bx * 32; br = by * 32;
    }
    for (int i = ty; i < 32; i += 8)
      tile[i][tx] = s[(size_t)(br + i) * cols + bc + tx];
    __syncthreads();
    for (int i = ty; i < 32; i += 8)
      d[(size_t)(bc + i) * rows + br + tx] = (f16)tile[tx][i];
  }
}

// ---------------- fused out GEMM ----------------
// out[z] = (pO[z] + pO[2+z]) @ woT^T + bo (f32), 128x128, BK=64, 8 waves.
// launch_bounds(512,2): cap VGPR so 2 blocks stay resident per CU and
// one block's A-sum staging overlaps the other's MFMA loop.

__global__ __launch_bounds__(512, 2) void out_fused(const f16* __restrict__ pO,
                                                    const f16* __restrict__ woT,
                                                    const float* __restrict__ bo,
                                                    float* __restrict__ out) {
  __shared__ __align__(16) f16 As[128 * 64];
  __shared__ __align__(16) f16 Bs[128 * 64];
  const int z = blockIdx.z;
  const size_t QS = (size_t)NROWS * DA;
  const f16* __restrict__ A0 = pO + (size_t)z * QS;
  const f16* __restrict__ A1 = pO + (size_t)(2 + z) * QS;
  float* __restrict__ Cg = out + (size_t)z * NROWS * DIN;

  int blkM, blkN;
  {
    const int gx = gridDim.x;
    const int nwg = gx * gridDim.y;
    const int lin = blockIdx.y * gx + blockIdx.x;
    const int q = nwg >> 3;
    const int nl = (lin & 7) * q + (lin >> 3);
    blkN = nl % gx;
    blkM = nl / gx;
  }

  const int tid = threadIdx.x;
  const int w = tid >> 6, lane = tid & 63;
  const int wr = w >> 2, wc = w & 3;
  const int lrow = lane & 15, lhi = lane >> 4;

  const size_t abase = (size_t)blkM * 128 * DA;
  const f16* Bbase = woT + (size_t)blkN * 128 * DA;

  f32x4 acc[4][2] = {};

  for (int kt = 0; kt < DA; kt += 64) {
#pragma unroll
    for (int it = 0; it < 2; ++it) {
      int cidx = (it * 8 + w) * 64 + lane;
      int row = cidx >> 3;
      int col = (cidx & 7) << 3;
      size_t off = abase + (size_t)row * DA + kt + col;
      f16x8 a = *(const f16x8*)(A0 + off);
      f16x8 b = *(const f16x8*)(A1 + off);
      f16x8 s;
#pragma unroll
      for (int j = 0; j < 8; ++j) s[j] = (f16)((float)a[j] + (float)b[j]);
      *(f16x8*)((char*)As + (size_t)cidx * 16) = s;
    }
#pragma unroll
    for (int it = 0; it < 2; ++it) {
      int cidx = (it * 8 + w) * 64 + lane;
      int row = cidx >> 3;
      int col = (cidx & 7) << 3;
      gload_lds16(Bbase + (size_t)row * DA + kt + col, (char*)Bs + (size_t)cidx * 16);
    }
    __syncthreads();

    f16x8 af[4][2], bfr[2][2];
#pragma unroll
    for (int m = 0; m < 4; ++m)
#pragma unroll
      for (int kk = 0; kk < 2; ++kk)
        af[m][kk] = *(const f16x8*)&As[(wr * 64 + m * 16 + lrow) * 64 + kk * 32 + lhi * 8];
#pragma unroll
    for (int n = 0; n < 2; ++n)
#pragma unroll
      for (int kk = 0; kk < 2; ++kk)
        bfr[n][kk] = *(const f16x8*)&Bs[(wc * 32 + n * 16 + lrow) * 64 + kk * 32 + lhi * 8];

#pragma unroll
    for (int m = 0; m < 4; ++m)
#pragma unroll
      for (int n = 0; n < 2; ++n)
#pragma unroll
        for (int kk = 0; kk < 2; ++kk)
          acc[m][n] = mfma16(af[m][kk], bfr[n][kk], acc[m][n]);
    __syncthreads();
  }

  const int row0 = blkM * 128 + wr * 64;
  const int col0 = blkN * 128 + wc * 32;
#pragma unroll
  for (int m = 0; m < 4; ++m)
#pragma unroll
    for (int n = 0; n < 2; ++n)
#pragma unroll
      for (int r = 0; r < 4; ++r) {
        int row = row0 + m * 16 + lhi * 4 + r;
        int col = col0 + n * 16 + lrow;
        Cg[(size_t)row * DIN + col] = acc[m][n][r] + bo[col];
      }
}

// ---------------- phased 256-row GEMM template ----------------
// C[256 x BN] = A[M,K] @ Bt[N,K]^T over K window [k0, k0+NT*BK).
// A addressing: element (row, k) at A[row*lda + k*aK].
// 8 waves (2M x 4N), M-interleaved wave frags. Double-buffered LDS,
// 1-tile-ahead staging with counted vmcnt; XOR swizzle + inverse-swizzled source.
// PH=4 (NFR=4 only): [B0,B1,A0,A1] one per phase. PH=2: [B..,A0 | A1].
// EPI 0: +bias; storebf=0 -> f16 row-major; storebf=1 (BN=256) -> bf16
//        TRANSPOSED store via LDS (for Vt)
// EPI 1: exp(), store bf16 into kc-TILED P layout + rowsum partials to rsO[z]
// EPI 2: split-K partial / rowsum (BLOCK-LOCAL reduce of rsO[z] partials
//        over NCHUNK chunks, cached in dead LDS), store f16

template <typename TIN>
struct G8Args {
  const TIN* A[6];
  const TIN* B[6];
  const float* bias[6];
  void* C[6];
  float* rsO[6];
  int k0[6];
  int storebf[6];
  int lda, ldb, ldc, aK;
};

template <typename TIN, int EPI, int BN, int NT, int BK = 64, int MINW = 1, int PH = 4>
__global__ __launch_bounds__(512, MINW) void g8(G8Args<TIN> args) {
  using vec8 = typename V8<TIN>::type;
  constexpr int NFR = BN / 64;
  constexpr int FPP = 8 / PH;
  constexpr int KK = BK / 32;
  constexpr int RB = BK * 2;
  constexpr int CPR = RB / 16;
  constexpr int SWM = CPR - 1;
  constexpr int SFT = (CPR == 4) ? 1 : 0;
  constexpr int ABUF = 256 * RB;
  constexpr int BBUF = BN * RB;
  constexpr int BUFSZ = ABUF + BBUF;
  constexpr int IPU = ABUF / 2 / 8192;
  __shared__ __align__(16) char smem[2 * BUFSZ];

  static_assert(PH == 4 || PH == 2, "PH in {2,4}");

  const int z = blockIdx.z;
  const TIN* __restrict__ A = args.A[z];
  const TIN* __restrict__ B = args.B[z];
  const int lda = args.lda, ldb = args.ldb, aK = args.aK;
  const int k0 = args.k0[z];

  int blkM, blkN;
  {
    const int gx = gridDim.x;
    const int nwg = gx * gridDim.y;
    const int lin = blockIdx.y * gx + blockIdx.x;
    const int q = nwg >> 3;
    const int nl = (lin & 7) * q + (lin >> 3);
    blkN = nl % gx;
    blkM = nl / gx;
  }

  const int tid = threadIdx.x;
  const int w = tid >> 6, lane = tid & 63;
  const int wm = w & 1, wn = w >> 1;
  const int lr = lane & 15, lh = lane >> 4;

  const TIN* Abase = A + (size_t)blkM * 256 * lda;
  const TIN* Bbase = B + (size_t)blkN * BN * ldb;

  f32x4 acc[8][NFR] = {};
  vec8 af[FPP][KK], bfr[NFR][KK];

#define SWZ(r_) (((r_) >> SFT) & SWM)
#define STAGE_A(buf, hf, kt)                                                    \
  {                                                                             \
    char* dst_ = smem + (buf)*BUFSZ + (hf)*(ABUF / 2);                          \
    const TIN* src_ = Abase + (size_t)((hf)*128) * lda + (size_t)(kt)*aK;       \
    _Pragma("unroll")                                                           \
    for (int i_ = 0; i_ < IPU; ++i_) {                                          \
      int c_ = i_ * 512 + tid;                                                  \
      int r_ = c_ / CPR, q_ = c_ % CPR;                                         \
      gload_lds16(src_ + (size_t)r_ * lda + ((q_ ^ SWZ(r_)) << 3),              \
                  dst_ + c_ * 16);                                              \
    }                                                                           \
  }
#define STAGE_B(buf, hf, kt)                                                    \
  {                                                                             \
    char* dst_ = smem + (buf)*BUFSZ + ABUF + (hf)*(ABUF / 2);                   \
    const TIN* src_ = Bbase + (size_t)((hf)*128) * ldb + (kt);                  \
    _Pragma("unroll")                                                           \
    for (int i_ = 0; i_ < IPU; ++i_) {                                          \
      int c_ = i_ * 512 + tid;                                                  \
      int r_ = c_ / CPR, q_ = c_ % CPR;                                         \
      gload_lds16(src_ + (size_t)r_ * ldb + ((q_ ^ SWZ(r_)) << 3),              \
                  dst_ + c_ * 16);                                              \
    }                                                                           \
  }
#define LDA_PHASE(buf, p)                                                       \
  {                                                                             \
    char* Ab_ = smem + (buf)*BUFSZ;                                             \
    _Pragma("unroll")                                                           \
    for (int fi_ = 0; fi_ < FPP; ++fi_) {                                       \
      int row_ = (((p)*FPP + fi_) * 2 + wm) * 16 + lr;                          \
      _Pragma("unroll")                                                         \
      for (int kk_ = 0; kk_ < KK; ++kk_) {                                      \
        int cc_ = (kk_ * 4 + lh) ^ SWZ(row_);                                   \
        af[fi_][kk_] = *(const vec8*)(Ab_ + row_ * RB + cc_ * 16);              \
      }                                                                         \
    }                                                                           \
  }
#define LDB_ALL(buf)                                                            \
  {                                                                             \
    char* Bb_ = smem + (buf)*BUFSZ + ABUF;                                      \
    _Pragma("unroll")                                                           \
    for (int n_ = 0; n_ < NFR; ++n_) {                                          \
      int row_ = wn * (BN / 4) + n_ * 16 + lr;                                  \
      _Pragma("unroll")                                                         \
      for (int kk_ = 0; kk_ < KK; ++kk_) {                                      \
        int cc_ = (kk_ * 4 + lh) ^ SWZ(row_);                                   \
        bfr[n_][kk_] = *(const vec8*)(Bb_ + row_ * RB + cc_ * 16);              \
      }                                                                         \
    }                                                                           \
  }
#define MFMA_PHASE(p)                                                           \
  {                                                                             \
    _Pragma("unroll")                                                           \
    for (int fi_ = 0; fi_ < FPP; ++fi_) {                                       \
      _Pragma("unroll")                                                         \
      for (int n_ = 0; n_ < NFR; ++n_) {                                        \
        _Pragma("unroll")                                                       \
        for (int kk_ = 0; kk_ < KK; ++kk_)                                      \
          acc[(p)*FPP + fi_][n_] = mfma16(af[fi_][kk_], bfr[n_][kk_],           \
                                          acc[(p)*FPP + fi_][n_]);              \
      }                                                                         \
    }                                                                           \
  }
#define BAR() __builtin_amdgcn_s_barrier()
#define LGK0()                                          \
  asm volatile("s_waitcnt lgkmcnt(0)" ::: "memory");    \
  __builtin_amdgcn_sched_barrier(0)

  if constexpr (NFR == 4) {
    STAGE_B(0, 0, k0); STAGE_B(0, 1, k0); STAGE_A(0, 0, k0); STAGE_A(0, 1, k0);
  } else {
    STAGE_B(0, 0, k0); STAGE_A(0, 0, k0); STAGE_A(0, 1, k0);
  }
  vmcnt_wait<IPU>();
  BAR();

  for (int t = 0; t < NT; ++t) {
    const int cur = t & 1, nxt = cur ^ 1;
    const int ktn = k0 + (t + 1) * BK;
    const bool st = (t < NT - 1);
    if constexpr (PH == 4) {
      if (st) { STAGE_B(nxt, 0, ktn); }
      LDB_ALL(cur);
      LDA_PHASE(cur, 0);
      BAR(); LGK0();
      __builtin_amdgcn_s_setprio(1); MFMA_PHASE(0); __builtin_amdgcn_s_setprio(0);
      BAR();
      if (st) { STAGE_B(nxt, 1, ktn); }
      LDA_PHASE(cur, 1);
      BAR(); LGK0();
      __builtin_amdgcn_s_setprio(1); MFMA_PHASE(1); __builtin_amdgcn_s_setprio(0);
      if (st) { vmcnt_wait<2 * IPU>(); }
      else    { vmcnt_wait<0>(); }
      BAR();
      if (st) { STAGE_A(nxt, 0, ktn); }
      LDA_PHASE(cur, 2);
      BAR(); LGK0();
      __builtin_amdgcn_s_setprio(1); MFMA_PHASE(2); __builtin_amdgcn_s_setprio(0);
      BAR();
      if (st) { STAGE_A(nxt, 1, ktn); }
      LDA_PHASE(cur, 3);
      BAR(); LGK0();
      __builtin_amdgcn_s_setprio(1); MFMA_PHASE(3); __builtin_amdgcn_s_setprio(0);
      if (st) { vmcnt_wait<IPU>(); }
      BAR();
    } else {
      if (st) {
        STAGE_B(nxt, 0, ktn);
        if constexpr (NFR == 4) { STAGE_B(nxt, 1, ktn); }
        STAGE_A(nxt, 0, ktn);
      }
      LDB_ALL(cur);
      LDA_PHASE(cur, 0);
      BAR(); LGK0();
      __builtin_amdgcn_s_setprio(1); MFMA_PHASE(0); __builtin_amdgcn_s_setprio(0);
      if (st) { vmcnt_wait<(NFR == 4 ? 3 : 2) * IPU>(); }
      else    { vmcnt_wait<0>(); }
      BAR();
      if (st) { STAGE_A(nxt, 1, ktn); }
      LDA_PHASE(cur, 1);
      BAR(); LGK0();
      __builtin_amdgcn_s_setprio(1); MFMA_PHASE(1); __builtin_amdgcn_s_setprio(0);
      if (st) { vmcnt_wait<IPU>(); }
      BAR();
    }
  }

  // ---- epilogue ----
  const int row0 = blkM * 256;
  const int col0 = blkN * BN + wn * (BN / 4);
  const int ldc = args.ldc;
  if constexpr (EPI == 1) {
    // exp + store into kc-tiled P [kc][4096][64] + rowsum partials.
    bf16* Pt = (bf16*)args.C[z] + (size_t)(blkN * 4 + wn) * ((size_t)NROWS * 64);
#pragma unroll
    for (int a = 0; a < 8; ++a) {
      float rsv[4] = {0.f, 0.f, 0.f, 0.f};
#pragma unroll
      for (int n = 0; n < NFR; ++n) {
#pragma unroll
        for (int rr = 0; rr < 4; ++rr) {
          int row = row0 + (a * 2 + wm) * 16 + lh * 4 + rr;
          float e = __expf(acc[a][n][rr]);
          Pt[(size_t)row * 64 + n * 16 + lr] = (bf16)e;
          rsv[rr] += e;
        }
      }
#pragma unroll
      for (int rr = 0; rr < 4; ++rr) {
        float s = rsv[rr];
        s += __shfl_xor(s, 1);
        s += __shfl_xor(s, 2);
        s += __shfl_xor(s, 4);
        s += __shfl_xor(s, 8);
        if (lr == 0) {
          int row = row0 + (a * 2 + wm) * 16 + lh * 4 + rr;
          args.rsO[z][((size_t)blkN * 4 + wn) * NROWS + row] = s;
        }
      }
    }
  } else if constexpr (EPI == 2) {
    // block-local rowsum reduce into dead LDS, then partial / rowsum, f16.
    float* rsinv = (float*)smem;
    if (tid < 256) {
      const float* p = args.rsO[z] + (row0 + tid);
      float s0 = 0.f, s1 = 0.f, s2 = 0.f, s3 = 0.f;
#pragma unroll
      for (int j = 0; j < NCHUNK; j += 4) {
        s0 += p[(size_t)j * NROWS];
        s1 += p[(size_t)(j + 1) * NROWS];
        s2 += p[(size_t)(j + 2) * NROWS];
        s3 += p[(size_t)(j + 3) * NROWS];
      }
      rsinv[tid] = 1.0f / ((s0 + s1) + (s2 + s3));
    }
    __syncthreads();
#pragma unroll
    for (int a = 0; a < 8; ++a) {
#pragma unroll
      for (int rr = 0; rr < 4; ++rr) {
        int row_l = (a * 2 + wm) * 16 + lh * 4 + rr;
        float rinv = rsinv[row_l];
#pragma unroll
        for (int n = 0; n < NFR; ++n) {
          int col = col0 + n * 16 + lr;
          ((f16*)args.C[z])[(size_t)(row0 + row_l) * ldc + col] =
              (f16)(acc[a][n][rr] * rinv);
        }
      }
    }
  } else if constexpr (EPI == 0 && BN == 256) {
    if (args.storebf[z]) {
      // bias + TRANSPOSED bf16 store via LDS (dest = vt[col][row], ld=NROWS).
#pragma unroll
      for (int a = 0; a < 8; ++a) {
#pragma unroll
        for (int n = 0; n < NFR; ++n) {
#pragma unroll
          for (int rr = 0; rr < 4; ++rr) {
            int row_l = (a * 2 + wm) * 16 + lh * 4 + rr;
            int col_l = wn * 64 + n * 16 + lr;
            float b = acc[a][n][rr] + args.bias[z][blkN * 256 + col_l];
            int byte = col_l * 512 + (((row_l >> 3) ^ (col_l & 31)) << 4) + (row_l & 7) * 2;
            *(bf16*)(smem + byte) = (bf16)b;
          }
        }
      }
      __syncthreads();
      bf16* vt = (bf16*)args.C[z];
#pragma unroll
      for (int i = 0; i < 16; ++i) {
        int cidx = i * 512 + tid;
        int c = cidx >> 5, ch = cidx & 31;
        u32x4 v = *(const u32x4*)(smem + c * 512 + ((ch ^ (c & 31)) << 4));
        size_t dst = (size_t)(blkN * 256 + c) * NROWS + blkM * 256 + ch * 8;
        *(u32x4*)(vt + dst) = v;
      }
    } else {
#pragma unroll
      for (int a = 0; a < 8; ++a) {
#pragma unroll
        for (int n = 0; n < NFR; ++n) {
#pragma unroll
          for (int rr = 0; rr < 4; ++rr) {
            int row = row0 + (a * 2 + wm) * 16 + lh * 4 + rr;
            int col = col0 + n * 16 + lr;
            ((f16*)args.C[z])[(size_t)row * ldc + col] =
                (f16)(acc[a][n][rr] + args.bias[z][col]);
          }
        }
      }
    }
  } else {
#pragma unroll
    for (int a = 0; a < 8; ++a) {
#pragma unroll
      for (int n = 0; n < NFR; ++n) {
#pragma unroll
        for (int rr = 0; rr < 4; ++rr) {
          int row = row0 + (a * 2 + wm) * 16 + lh * 4 + rr;
          int col = col0 + n * 16 + lr;
          float v = acc[a][n][rr];
          if constexpr (EPI == 0) {
            ((f16*)args.C[z])[(size_t)row * ldc + col] = (f16)(v + args.bias[z][col]);
          } else {
            ((float*)args.C[z])[(size_t)row * ldc + col] = v + args.bias[z][col];
          }
        }
      }
    }
  }
#undef SWZ
#undef STAGE_A
#undef STAGE_B
#undef LDA_PHASE
#undef LDB_ALL
#undef MFMA_PHASE
#undef BAR
#undef LGK0
}

// ---------------- launch ----------------

extern "C" void kernel_launch(void* const* d_in, const int* in_sizes, int n_in,
                              void* d_out, int out_size, void* d_ws, size_t ws_size,
                              hipStream_t stream) {
  const float* in1 = (const float*)d_in[0];
  const float* in2 = (const float*)d_in[1];
  const float* Wq = (const float*)d_in[2];
  const float* bq = (const float*)d_in[3];
  const float* Wk = (const float*)d_in[4];
  const float* bk = (const float*)d_in[5];
  const float* Wv = (const float*)d_in[6];
  const float* bv = (const float*)d_in[7];
  const float* Wo = (const float*)d_in[8];
  const float* bo = (const float*)d_in[9];
  float* out = (float*)d_out;

  const size_t IN_E = (size_t)NROWS * DIN;   // 4M
  const size_t WT_E = (size_t)DA * DIN;      // 512K
  const size_t QS = (size_t)NROWS * DA;      // 2M
  const size_t PS = (size_t)NROWS * NROWS;   // 16M

  f16* qk = (f16*)d_ws;                      // 16 MB (dead after QK)
  f16* in_hf = qk + 4 * QS;                  // 16 MB (dead after proj)
  bf16* vv = (bf16*)(in_hf + 2 * IN_E);      // 8 MB (rowsum scratch)
  f16* wt = (f16*)(vv + 2 * QS);             // 3 MB
  f16* woT = wt + 3 * WT_E;                  // 1 MB
  bf16* vt = (bf16*)(woT + WT_E);            // 8 MB (written directly by proj)
  bf16* P = vt + 2 * QS;                     // 64 MB, kc-tiled [kc][4096][64]
  f16* pO = (f16*)d_ws;                      // 16 MB f16 (4 slices), aliases qk
  float* prsP = (float*)vv;                  // 2 MB rowsum partials

  // 1. unified prep: cast inputs + transpose-cast weights (single launch)
  prep_kernel<<<dim3(10240), dim3(256), 0, stream>>>(
      in1, in2, Wq, Wk, Wv, Wo, in_hf, wt, woT);

  // 2. projections (2-phase 256x256): z = Q1,K1,Q2,K2,V1,V2
  //    V (z=4,5) stored DIRECTLY TRANSPOSED into vt (bf16) via LDS epilogue.
  {
    G8Args<f16> a{};
    const float* bs[3] = {bq, bk, bv};
    for (int zi = 0; zi < 6; ++zi) {
      int which = (zi < 4) ? (zi & 1) : 2;
      int src = (zi < 4) ? (zi >> 1) : (zi - 4);
      a.A[zi] = in_hf + (size_t)src * IN_E;
      a.B[zi] = wt + (size_t)which * WT_E;
      a.bias[zi] = bs[which];
      a.C[zi] = (zi < 4) ? (void*)(qk + (size_t)zi * QS) : (void*)(vt + (size_t)(zi - 4) * QS);
      a.storebf[zi] = (zi >= 4);
      a.k0[zi] = 0;
    }
    a.lda = DIN; a.ldb = DIN; a.ldc = DA; a.aK = 1;
    g8<f16, 0, 256, 16, 64, 1, 2><<<dim3(2, 16, 6), dim3(512), 0, stream>>>(a);
  }

  // 3. P = exp(Q @ K^T) into kc-tiled layout + rowsum partials (2-phase 256x256)
  {
    G8Args<f16> a{};
    a.A[0] = qk + 0 * QS; a.B[0] = qk + 3 * QS; a.C[0] = P;
    a.A[1] = qk + 2 * QS; a.B[1] = qk + 1 * QS; a.C[1] = P + PS;
    a.rsO[0] = prsP;
    a.rsO[1] = prsP + (size_t)NCHUNK * NROWS;
    a.k0[0] = a.k0[1] = 0;
    a.lda = DA; a.ldb = DA; a.ldc = NROWS; a.aK = 1;
    g8<f16, 1, 256, 8, 64, 1, 2><<<dim3(16, 16, 2), dim3(512), 0, stream>>>(a);
  }

  // 4. PV split-K partials, block-local rowsum reduce, f16 (2-phase 256x128)
  {
    G8Args<bf16> a{};
    for (int i = 0; i < 4; ++i) {
      int pair = i & 1, s = i >> 1;
      a.A[i] = P + (size_t)pair * PS;
      a.B[i] = vt + (size_t)(pair ^ 1) * QS;
      a.C[i] = pO + (size_t)i * QS;
      a.rsO[i] = prsP + (size_t)pair * NCHUNK * NROWS;
      a.k0[i] = s * 2048;
      a.storebf[i] = 0;
    }
    a.lda = 64; a.ldb = NROWS; a.ldc = DA; a.aK = NROWS;
    g8<bf16, 2, 128, 32, 64, 1, 2><<<dim3(4, 16, 4), dim3(512), 0, stream>>>(a);
  }

  // 5. out = (pO[z]+pO[2+z]) @ Wo + bo (fused merge + GEMM, f32)
  out_fused<<<dim3(DIN / 128, NROWS / 128, 2), dim3(512), 0, stream>>>(
      pO, woT, bo, out);
}